// Round 5
// baseline (428.951 us; speedup 1.0000x reference)
//
#include <hip/hip_runtime.h>
#include <hip/hip_bf16.h>

#define NNODES 50000
#define NEDGES 800000
#define IN_DIM 128
#define EDGE_DIM 32
#define OUT_DIM 128
#define KDIM 160          // IN_DIM + EDGE_DIM
#define A_STRIDE 168      // 160 + 8 pad, 16B aligned rows
#define NS 136            // 128 + 8 pad for node kernel
#define MT_STRIDE 72      // col-major m-tile: 72 shorts = 144 B (16B-aligned rows)
#define NT (NEDGES / 64)  // 12500 edge tiles
#define EG 768            // edge grid: 3 blocks/CU, strided tile assignment

typedef __attribute__((ext_vector_type(8))) short short8;
typedef __attribute__((ext_vector_type(4))) short short4v;
typedef __attribute__((ext_vector_type(4))) float floatx4;

__device__ __forceinline__ short f2bf(float f) {
    union { float f; unsigned u; } v; v.f = f;
    unsigned r = (v.u + 0x7FFFu + ((v.u >> 16) & 1u)) >> 16;  // RNE
    return (short)r;
}

__device__ __forceinline__ void store_bf4(short* p, floatx4 v) {
    short4v s;
    s.x = f2bf(v.x); s.y = f2bf(v.y); s.z = f2bf(v.z); s.w = f2bf(v.w);
    *(short4v*)p = s;
}

__device__ __forceinline__ void store_bf8(short* p, floatx4 a, floatx4 b) {
    short8 s;
    s[0] = f2bf(a.x); s[1] = f2bf(a.y); s[2] = f2bf(a.z); s[3] = f2bf(a.w);
    s[4] = f2bf(b.x); s[5] = f2bf(b.y); s[6] = f2bf(b.z); s[7] = f2bf(b.w);
    *(short8*)p = s;
}

#define MFMA8(ACC, A0, A1, B0, B1, B2, B3)                                        \
    ACC[0][0] = __builtin_amdgcn_mfma_f32_16x16x32_bf16(A0, B0, ACC[0][0], 0, 0, 0); \
    ACC[0][1] = __builtin_amdgcn_mfma_f32_16x16x32_bf16(A0, B1, ACC[0][1], 0, 0, 0); \
    ACC[0][2] = __builtin_amdgcn_mfma_f32_16x16x32_bf16(A0, B2, ACC[0][2], 0, 0, 0); \
    ACC[0][3] = __builtin_amdgcn_mfma_f32_16x16x32_bf16(A0, B3, ACC[0][3], 0, 0, 0); \
    ACC[1][0] = __builtin_amdgcn_mfma_f32_16x16x32_bf16(A1, B0, ACC[1][0], 0, 0, 0); \
    ACC[1][1] = __builtin_amdgcn_mfma_f32_16x16x32_bf16(A1, B1, ACC[1][1], 0, 0, 0); \
    ACC[1][2] = __builtin_amdgcn_mfma_f32_16x16x32_bf16(A1, B2, ACC[1][2], 0, 0, 0); \
    ACC[1][3] = __builtin_amdgcn_mfma_f32_16x16x32_bf16(A1, B3, ACC[1][3], 0, 0, 0);

// ---------------------------------------------------------------------------
// Prep: nfeat -> bf16 table, folded weights, AND dst histogram.
// (cnt and out pre-zeroed by hipMemsetAsync before this kernel.)
// ---------------------------------------------------------------------------
__global__ __launch_bounds__(256) void prep_kernel(
    const float* __restrict__ nfeat, const int* __restrict__ dst,
    const float* __restrict__ W_edge, const float* __restrict__ W_ne,
    const float* __restrict__ W_self,
    int* __restrict__ cnt, short* __restrict__ nfB,
    short* __restrict__ WcatB, short* __restrict__ WselfB)
{
    int gid = blockIdx.x * 256 + threadIdx.x;
    int GS = gridDim.x * 256;
    for (int i = gid; i < NNODES * IN_DIM / 8; i += GS) {
        floatx4 a = ((const floatx4*)nfeat)[2 * i];
        floatx4 b = ((const floatx4*)nfeat)[2 * i + 1];
        store_bf8(nfB + 8 * i, a, b);
    }
    for (int idx = gid; idx < OUT_DIM * KDIM + OUT_DIM * IN_DIM; idx += GS) {
        if (idx < OUT_DIM * KDIM) {
            int n = idx / KDIM, k = idx - n * KDIM;
            float val;
            if (k < IN_DIM) {
                val = W_ne[n * 256 + k];
            } else {
                int j = k - IN_DIM;
                float s = 0.f;
                for (int kk = 0; kk < 128; ++kk)
                    s += W_ne[n * 256 + 128 + kk] * W_edge[kk * 32 + j];
                val = s;
            }
            WcatB[idx] = f2bf(val);
        } else {
            int s = idx - OUT_DIM * KDIM;
            WselfB[s] = f2bf(W_self[s]);
        }
    }
    for (int e = gid; e < NEDGES; e += GS)
        atomicAdd(&cnt[dst[e]], 1);
}

// ---------------------------------------------------------------------------
// Counting sort: scan (single block) then scatter.
// ---------------------------------------------------------------------------
__global__ __launch_bounds__(1024) void scan_kernel(const int* __restrict__ cnt,
                                                    int* __restrict__ cur) {
    __shared__ int bufA[1024], bufB[1024];
    const int CH = 49;                       // 49*1024 >= 50000
    int t = threadIdx.x;
    int beg = t * CH, end = min(beg + CH, NNODES);
    int s = 0;
    for (int i = beg; i < end; ++i) s += cnt[i];
    bufA[t] = s;
    __syncthreads();
    int* in = bufA; int* out = bufB;
    for (int off = 1; off < 1024; off <<= 1) {
        out[t] = in[t] + (t >= off ? in[t - off] : 0);
        __syncthreads();
        int* tmp = in; in = out; out = tmp;
    }
    int base = in[t] - s;
    for (int i = beg; i < end; ++i) { cur[i] = base; base += cnt[i]; }
}

// Scatter: place packed (src|dst<<16) record at sorted position AND gather
// the edge's etype row (bf16-converted) to the same sorted position.
// etype read is SEQUENTIAL (by e); the 4B + 64B writes are random but
// fire-and-forget. This converts edge_kernel's 102 MB random 128-B etype
// gather into a 51 MB sequential bf16 read.
__global__ void scatter_kernel(const int* __restrict__ src,
                               const int* __restrict__ dst,
                               const float* __restrict__ etype,
                               int* __restrict__ cur,      // cursor (destroyed)
                               int* __restrict__ esd, short* __restrict__ escT) {
    int e = blockIdx.x * 256 + threadIdx.x;
    if (e < NEDGES) {
        int d = dst[e];
        int s = src[e];
        int pos = atomicAdd(&cur[d], 1);
        esd[pos] = (int)((unsigned)s | ((unsigned)d << 16));
        const floatx4* er = (const floatx4*)(etype + (size_t)e * 32);
        short* op = escT + (size_t)pos * 32;
        #pragma unroll
        for (int i = 0; i < 4; ++i) {
            floatx4 a = er[2 * i];
            floatx4 b = er[2 * i + 1];
            store_bf8(op + 8 * i, a, b);
        }
    }
}

// ---------------------------------------------------------------------------
// Edge kernel: persistent, strided tiles, 3 blocks/CU. R4 geometry (proven
// no-spill: always-live ~105 regs under (256,3)). Per-tile inputs are now
// fully sorted+sequential: esd (4 B/edge) + escT (64 B/edge bf16 etype);
// only the nfB row gather remains random (L2/L3-absorbed).
// Software pipeline (T14 async-stage split):
//   pv* (nfB) + pe (escT) hold tile t+EG's data (record rsd); psd holds the
//   record for tile t+2EG.  Per iteration:
//     sync1 (lgkm-only raw barrier; prefetch loads stay in flight)
//     setprio(1) MFMA(t) setprio(0) -> relu+bias -> mT writes
//     sync2 (lgkm-only)
//     stage(t+EG) from regs + dstL[nb] from rsd; issue gathers for t+2EG
//     scan(t): dsts from LDS broadcast + readfirstlane -> SCALAR run
//       detection -> one atomicMax per run.
// LDS: As 21504 + mT 18432 + dstL 256 = 40192 B -> 3 blocks/CU.
// ---------------------------------------------------------------------------
__global__ __launch_bounds__(256, 3) void edge_kernel(
    const short* __restrict__ nfB, const short* __restrict__ escT,
    const int* __restrict__ esd, const float* __restrict__ b_ne,
    const short* __restrict__ WcatB, float* __restrict__ out)
{
    __shared__ short As[64 * A_STRIDE];            // 21504 B
    __shared__ unsigned short mT[128 * MT_STRIDE]; // 18432 B, col-major [o][el]
    __shared__ short dstL[2][64];                  // 256 B, double-buffered dsts

    const int tid = threadIdx.x;
    const int lane = tid & 63;
    const int w = tid >> 6;                        // wave id: cols w*32..w*32+31
    const int li = lane & 15, q = lane >> 4;

    // --- B-fragments to registers (once per block; L2-hot) ---
    short8 bf[2][5];
    #pragma unroll
    for (int ct = 0; ct < 2; ++ct)
        #pragma unroll
        for (int kk = 0; kk < 5; ++kk)
            bf[ct][kk] = *(const short8*)(WcatB +
                (size_t)(w * 32 + ct * 16 + li) * KDIM + kk * 32 + q * 8);

    float bias[2];
    #pragma unroll
    for (int ct = 0; ct < 2; ++ct) bias[ct] = b_ne[w * 32 + ct * 16 + li];

    const int ee = tid >> 2, ec = tid & 3;         // 4 threads per edge row

    short8 pv0, pv1, pv2, pv3;                     // prefetched nfB row quarter
    short8 pe;                                     // prefetched escT quarter
    int rsd = 0;                                   // record matching pv*/pe
    int psd = 0;                                   // record for t+2EG

    const int tA = blockIdx.x;                     // first tile (strided by EG)

    // --- prologue: stage tile tA; load heavy(tA+EG); psd = rec(tA+2EG) ---
    {
        int sd = esd[tA * 64 + ee];
        int s = sd & 0xFFFF;
        const short8* nr = (const short8*)(nfB + (size_t)s * 128);
        pv0 = nr[4 * ec]; pv1 = nr[4 * ec + 1];
        pv2 = nr[4 * ec + 2]; pv3 = nr[4 * ec + 3];
        pe = *(const short8*)(escT + (size_t)(tA * 64 + ee) * 32 + ec * 8);

        int tB = tA + EG;
        int sdB = 0;
        if (tB < NT) sdB = esd[tB * 64 + ee];

        short* ap = As + ee * A_STRIDE + 32 * ec;
        *(short8*)(ap)      = pv0;
        *(short8*)(ap + 8)  = pv1;
        *(short8*)(ap + 16) = pv2;
        *(short8*)(ap + 24) = pv3;
        *(short8*)(As + ee * A_STRIDE + IN_DIM + 8 * ec) = pe;
        if (ec == 0) dstL[0][ee] = (short)((unsigned)sd >> 16);

        if (tB < NT) {
            int sB = sdB & 0xFFFF;
            const short8* nrB = (const short8*)(nfB + (size_t)sB * 128);
            pv0 = nrB[4 * ec]; pv1 = nrB[4 * ec + 1];
            pv2 = nrB[4 * ec + 2]; pv3 = nrB[4 * ec + 3];
            pe = *(const short8*)(escT + (size_t)(tB * 64 + ee) * 32 + ec * 8);
            rsd = sdB;
            int tC = tB + EG;
            if (tC < NT) psd = esd[tC * 64 + ee];
        }
    }

    int it = 0;
    for (int t = tA; t < NT; t += EG, ++it) {
        const int cb = it & 1, nb = cb ^ 1;

        // sync1: As(t)/dstL(t) visible. lgkm-only: prefetch stays in flight.
        asm volatile("s_waitcnt lgkmcnt(0)" ::: "memory");
        __builtin_amdgcn_s_barrier();

        floatx4 acc[4][2];                         // [row-tile][col-tile]
        #pragma unroll
        for (int i = 0; i < 4; ++i)
            #pragma unroll
            for (int j = 0; j < 2; ++j)
                acc[i][j] = (floatx4){0.f, 0.f, 0.f, 0.f};

        __builtin_amdgcn_s_setprio(1);
        #pragma unroll
        for (int kk = 0; kk < 5; ++kk) {
            short8 a0 = *(const short8*)(As + (0 * 16 + li) * A_STRIDE + kk * 32 + q * 8);
            short8 a1 = *(const short8*)(As + (1 * 16 + li) * A_STRIDE + kk * 32 + q * 8);
            short8 a2 = *(const short8*)(As + (2 * 16 + li) * A_STRIDE + kk * 32 + q * 8);
            short8 a3 = *(const short8*)(As + (3 * 16 + li) * A_STRIDE + kk * 32 + q * 8);
            acc[0][0] = __builtin_amdgcn_mfma_f32_16x16x32_bf16(a0, bf[0][kk], acc[0][0], 0, 0, 0);
            acc[0][1] = __builtin_amdgcn_mfma_f32_16x16x32_bf16(a0, bf[1][kk], acc[0][1], 0, 0, 0);
            acc[1][0] = __builtin_amdgcn_mfma_f32_16x16x32_bf16(a1, bf[0][kk], acc[1][0], 0, 0, 0);
            acc[1][1] = __builtin_amdgcn_mfma_f32_16x16x32_bf16(a1, bf[1][kk], acc[1][1], 0, 0, 0);
            acc[2][0] = __builtin_amdgcn_mfma_f32_16x16x32_bf16(a2, bf[0][kk], acc[2][0], 0, 0, 0);
            acc[2][1] = __builtin_amdgcn_mfma_f32_16x16x32_bf16(a2, bf[1][kk], acc[2][1], 0, 0, 0);
            acc[3][0] = __builtin_amdgcn_mfma_f32_16x16x32_bf16(a3, bf[0][kk], acc[3][0], 0, 0, 0);
            acc[3][1] = __builtin_amdgcn_mfma_f32_16x16x32_bf16(a3, bf[1][kk], acc[3][1], 0, 0, 0);
        }
        __builtin_amdgcn_s_setprio(0);

        // --- relu+bias -> col-major mT; C/D: row = q*4+r, col = li ---
        #pragma unroll
        for (int rt = 0; rt < 4; ++rt) {
            #pragma unroll
            for (int ct = 0; ct < 2; ++ct) {
                floatx4 a = acc[rt][ct];
                short4v s;
                float v0 = a.x + bias[ct]; s.x = f2bf(v0 > 0.f ? v0 : 0.f);
                float v1 = a.y + bias[ct]; s.y = f2bf(v1 > 0.f ? v1 : 0.f);
                float v2 = a.z + bias[ct]; s.z = f2bf(v2 > 0.f ? v2 : 0.f);
                float v3 = a.w + bias[ct]; s.w = f2bf(v3 > 0.f ? v3 : 0.f);
                *(short4v*)((short*)mT + (w * 32 + ct * 16 + li) * MT_STRIDE
                            + rt * 16 + q * 4) = s;
            }
        }
        // sync2: mT(t) visible; all waves done reading As(t).
        asm volatile("s_waitcnt lgkmcnt(0)" ::: "memory");
        __builtin_amdgcn_s_barrier();

        // --- stage tile t+EG from regs; issue gathers for t+2EG ---
        {
            int tn = t + EG;
            if (tn < NT) {
                short* ap = As + ee * A_STRIDE + 32 * ec;
                *(short8*)(ap)      = pv0;
                *(short8*)(ap + 8)  = pv1;
                *(short8*)(ap + 16) = pv2;
                *(short8*)(ap + 24) = pv3;
                *(short8*)(As + ee * A_STRIDE + IN_DIM + 8 * ec) = pe;
                if (ec == 0) dstL[nb][ee] = (short)((unsigned)rsd >> 16);

                int sd2 = psd;
                int t2 = tn + EG;
                if (t2 < NT) {
                    int t3 = t2 + EG;
                    if (t3 < NT) psd = esd[t3 * 64 + ee];
                    int s2 = sd2 & 0xFFFF;
                    const short8* nr2 = (const short8*)(nfB + (size_t)s2 * 128);
                    pv0 = nr2[4 * ec]; pv1 = nr2[4 * ec + 1];
                    pv2 = nr2[4 * ec + 2]; pv3 = nr2[4 * ec + 3];
                    pe = *(const short8*)(escT + (size_t)(t2 * 64 + ee) * 32 + ec * 8);
                    rsd = sd2;
                }
            }
        }
        __builtin_amdgcn_sched_barrier(0);  // keep prefetch issue ahead of scan

        // --- per-column run-max; dsts from LDS broadcast, SCALAR control ---
        {
            int c = tid & 127, h = tid >> 7;
            int r0 = h * 32;
            unsigned mval[32];
            #pragma unroll
            for (int j = 0; j < 4; ++j) {
                short8 v = *(const short8*)((const short*)mT + c * MT_STRIDE
                                            + r0 + 8 * j);
                #pragma unroll
                for (int k = 0; k < 8; ++k)
                    mval[8 * j + k] = (unsigned short)v[k];
            }
            const short8* dls = (const short8*)(&dstL[cb][r0]);
            int curd = 0;
            unsigned best = 0;
            #pragma unroll
            for (int j = 0; j < 4; ++j) {
                short8 dv = dls[j];
                #pragma unroll
                for (int k = 0; k < 8; ++k) {
                    int r = 8 * j + k;
                    int d = __builtin_amdgcn_readfirstlane(
                        (int)(unsigned short)dv[k]);
                    if (r == 0) {
                        curd = d; best = mval[0];
                    } else if (d != curd) {
                        atomicMax((int*)out + (size_t)curd * 128 + c,
                                  (int)(best << 16));
                        curd = d; best = mval[r];
                    } else {
                        best = best > mval[r] ? best : mval[r];
                    }
                }
            }
            atomicMax((int*)out + (size_t)curd * 128 + c, (int)(best << 16));
        }
    }
}

// ---------------------------------------------------------------------------
// Node kernel (in-place): out = (1+eps)*out + nfeat @ W_self^T + b_self
// ---------------------------------------------------------------------------
__global__ __launch_bounds__(256) void node_kernel(
    const short* __restrict__ nfB, const float* __restrict__ b_self,
    const float* __restrict__ eps, const short* __restrict__ WselfB,
    float* __restrict__ out)
{
    __shared__ short As[64 * NS];
    __shared__ short Bs[128 * NS];
    const int tid = threadIdx.x;
    const int n0 = blockIdx.x * 64;

    {
        int r = tid >> 1, h = tid & 1;
        const short8* g = (const short8*)(WselfB + r * 128 + h * 64);
        short* l = Bs + r * NS + h * 64;
        #pragma unroll
        for (int c = 0; c < 8; ++c)
            *(short8*)(l + 8 * c) = g[c];
    }
    {
        int r = tid >> 2, c = tid & 3;
        int n = n0 + r;
        short* ap = As + r * NS + 32 * c;
        if (n < NNODES) {
            const short8* nr = (const short8*)(nfB + (size_t)n * 128);
            #pragma unroll
            for (int j = 0; j < 4; ++j)
                *(short8*)(ap + 8 * j) = nr[4 * c + j];
        } else {
            #pragma unroll
            for (int j = 0; j < 4; ++j)
                *(short8*)(ap + 8 * j) = (short8){0,0,0,0,0,0,0,0};
        }
    }
    __syncthreads();

    const int lane = tid & 63;
    const int w = tid >> 6;
    const int et = w & 1;
    const int nh = w >> 1;
    const int li = lane & 15, q = lane >> 4;

    floatx4 acc[2][4];
    #pragma unroll
    for (int i = 0; i < 2; ++i)
        #pragma unroll
        for (int j = 0; j < 4; ++j)
            acc[i][j] = (floatx4){0.f, 0.f, 0.f, 0.f};

    const short* Ab = As + (et * 32 + li) * NS + q * 8;
    const short* Bb = Bs + (nh * 64 + li) * NS + q * 8;
    #pragma unroll
    for (int kk = 0; kk < 4; ++kk) {
        short8 a0 = *(const short8*)(Ab + kk * 32);
        short8 a1 = *(const short8*)(Ab + 16 * NS + kk * 32);
        short8 b0 = *(const short8*)(Bb + kk * 32);
        short8 b1 = *(const short8*)(Bb + 16 * NS + kk * 32);
        short8 b2 = *(const short8*)(Bb + 32 * NS + kk * 32);
        short8 b3 = *(const short8*)(Bb + 48 * NS + kk * 32);
        MFMA8(acc, a0, a1, b0, b1, b2, b3)
    }

    const float epsv = 1.0f + eps[0];
    #pragma unroll
    for (int ta = 0; ta < 2; ++ta) {
        #pragma unroll
        for (int r = 0; r < 4; ++r) {
            int n = n0 + et * 32 + ta * 16 + q * 4 + r;
            if (n < NNODES) {
                #pragma unroll
                for (int tb = 0; tb < 4; ++tb) {
                    int o = nh * 64 + tb * 16 + li;
                    float v = acc[ta][tb][r] + b_self[o]
                            + epsv * out[(size_t)n * 128 + o];
                    out[(size_t)n * 128 + o] = v;
                }
            }
        }
    }
}

// ===========================================================================
// Fallback kernels (direct path) — used only if ws_size too small.
// ===========================================================================
__global__ void prep_w(const float* __restrict__ W_edge,
                       const float* __restrict__ W_ne,
                       const float* __restrict__ W_self,
                       short* __restrict__ WcatB, short* __restrict__ WselfB)
{
    int idx = blockIdx.x * 256 + threadIdx.x;
    if (idx < OUT_DIM * KDIM) {
        int n = idx / KDIM, k = idx - n * KDIM;
        float val;
        if (k < IN_DIM) {
            val = W_ne[n * 256 + k];
        } else {
            int j = k - IN_DIM;
            float s = 0.f;
            for (int kk = 0; kk < 128; ++kk)
                s += W_ne[n * 256 + 128 + kk] * W_edge[kk * 32 + j];
            val = s;
        }
        WcatB[idx] = f2bf(val);
    } else if (idx < OUT_DIM * KDIM + OUT_DIM * IN_DIM) {
        int s = idx - OUT_DIM * KDIM;
        WselfB[s] = f2bf(W_self[s]);
    }
}

__global__ __launch_bounds__(256) void edge_direct(
    const float* __restrict__ nfeat, const float* __restrict__ etype,
    const int* __restrict__ src, const int* __restrict__ dst,
    const float* __restrict__ b_ne, const short* __restrict__ WcatB,
    float* __restrict__ out)
{
    __shared__ short As[64 * A_STRIDE];
    __shared__ short Bs[128 * A_STRIDE];
    const int tid = threadIdx.x;
    const int e0 = blockIdx.x * 64;
    {
        int r = tid >> 1, h = tid & 1;
        const short8* g = (const short8*)(WcatB + r * KDIM + h * 80);
        short* l = Bs + r * A_STRIDE + h * 80;
        #pragma unroll
        for (int c = 0; c < 10; ++c) *(short8*)(l + 8 * c) = g[c];
    }
    {
        const floatx4* ge = (const floatx4*)(etype + (size_t)e0 * 32);
        #pragma unroll
        for (int i = 0; i < 2; ++i) {
            int f = tid + i * 256;
            int e = f >> 3, c = f & 7;
            store_bf4(As + e * A_STRIDE + IN_DIM + 4 * c, ge[f]);
        }
    }
    {
        int g = tid & 15, eo = tid >> 4;
        #pragma unroll
        for (int p = 0; p < 4; ++p) {
            int e = eo + p * 16;
            int s = src[e0 + e];
            const floatx4* row = (const floatx4*)(nfeat + (size_t)s * 128);
            floatx4 v0 = row[g];
            floatx4 v1 = row[g + 16];
            store_bf4(As + e * A_STRIDE + 4 * g, v0);
            store_bf4(As + e * A_STRIDE + 64 + 4 * g, v1);
        }
    }
    __syncthreads();
    const int lane = tid & 63;
    const int w = tid >> 6;
    const int et = w & 1, nh = w >> 1;
    const int li = lane & 15, q = lane >> 4;
    floatx4 acc[2][4];
    #pragma unroll
    for (int i = 0; i < 2; ++i)
        #pragma unroll
        for (int j = 0; j < 4; ++j)
            acc[i][j] = (floatx4){0.f, 0.f, 0.f, 0.f};
    const short* Ab = As + (et * 32 + li) * A_STRIDE + q * 8;
    const short* Bb = Bs + (nh * 64 + li) * A_STRIDE + q * 8;
    #pragma unroll
    for (int kk = 0; kk < 5; ++kk) {
        short8 a0 = *(const short8*)(Ab + kk * 32);
        short8 a1 = *(const short8*)(Ab + 16 * A_STRIDE + kk * 32);
        short8 b0 = *(const short8*)(Bb + kk * 32);
        short8 b1 = *(const short8*)(Bb + 16 * A_STRIDE + kk * 32);
        short8 b2 = *(const short8*)(Bb + 32 * A_STRIDE + kk * 32);
        short8 b3 = *(const short8*)(Bb + 48 * A_STRIDE + kk * 32);
        MFMA8(acc, a0, a1, b0, b1, b2, b3)
    }
    #pragma unroll
    for (int ta = 0; ta < 2; ++ta) {
        #pragma unroll
        for (int r = 0; r < 4; ++r) {
            int el = et * 32 + ta * 16 + q * 4 + r;
            int d = dst[e0 + el];
            int* nrow = (int*)out + (size_t)d * 128;
            #pragma unroll
            for (int tb = 0; tb < 4; ++tb) {
                int o = nh * 64 + tb * 16 + li;
                float v = acc[ta][tb][r] + b_ne[o];
                v = v > 0.f ? v : 0.f;
                atomicMax(nrow + o, __float_as_int(v));
            }
        }
    }
}

__global__ __launch_bounds__(256) void node_direct(
    const float* __restrict__ nfeat, const float* __restrict__ b_self,
    const float* __restrict__ eps, const short* __restrict__ WselfB,
    float* __restrict__ out)
{
    __shared__ short As[64 * NS];
    __shared__ short Bs[128 * NS];
    const int tid = threadIdx.x;
    const int n0 = blockIdx.x * 64;
    {
        int r = tid >> 1, h = tid & 1;
        const short8* g = (const short8*)(WselfB + r * 128 + h * 64);
        short* l = Bs + r * NS + h * 64;
        #pragma unroll
        for (int c = 0; c < 8; ++c) *(short8*)(l + 8 * c) = g[c];
    }
    {
        int r = tid >> 2, fi = tid & 3;
        int n = n0 + r;
        if (n < NNODES) {
            const floatx4* row = (const floatx4*)(nfeat + (size_t)n * 128);
            #pragma unroll
            for (int p = 0; p < 8; ++p) {
                int f = fi + 4 * p;
                store_bf4(As + r * NS + 4 * f, row[f]);
            }
        } else {
            #pragma unroll
            for (int p = 0; p < 8; ++p) {
                int f = fi + 4 * p;
                *(short4v*)(As + r * NS + 4 * f) = (short4v){0, 0, 0, 0};
            }
        }
    }
    __syncthreads();
    const int lane = tid & 63;
    const int w = tid >> 6;
    const int et = w & 1, nh = w >> 1;
    const int li = lane & 15, q = lane >> 4;
    floatx4 acc[2][4];
    #pragma unroll
    for (int i = 0; i < 2; ++i)
        #pragma unroll
        for (int j = 0; j < 4; ++j)
            acc[i][j] = (floatx4){0.f, 0.f, 0.f, 0.f};
    const short* Ab = As + (et * 32 + li) * NS + q * 8;
    const short* Bb = Bs + (nh * 64 + li) * NS + q * 8;
    #pragma unroll
    for (int kk = 0; kk < 4; ++kk) {
        short8 a0 = *(const short8*)(Ab + kk * 32);
        short8 a1 = *(const short8*)(Ab + 16 * NS + kk * 32);
        short8 b0 = *(const short8*)(Bb + kk * 32);
        short8 b1 = *(const short8*)(Bb + 16 * NS + kk * 32);
        short8 b2 = *(const short8*)(Bb + 32 * NS + kk * 32);
        short8 b3 = *(const short8*)(Bb + 48 * NS + kk * 32);
        MFMA8(acc, a0, a1, b0, b1, b2, b3)
    }
    const float epsv = 1.0f + eps[0];
    #pragma unroll
    for (int ta = 0; ta < 2; ++ta) {
        #pragma unroll
        for (int r = 0; r < 4; ++r) {
            int n = n0 + et * 32 + ta * 16 + q * 4 + r;
            if (n < NNODES) {
                #pragma unroll
                for (int tb = 0; tb < 4; ++tb) {
                    int o = nh * 64 + tb * 16 + li;
                    float v = acc[ta][tb][r] + b_self[o]
                            + epsv * out[(size_t)n * 128 + o];
                    out[(size_t)n * 128 + o] = v;
                }
            }
        }
    }
}

// ---------------------------------------------------------------------------
extern "C" void kernel_launch(void* const* d_in, const int* in_sizes, int n_in,
                              void* d_out, int out_size, void* d_ws, size_t ws_size,
                              hipStream_t stream) {
    const float* nfeat  = (const float*)d_in[0];
    const float* etype  = (const float*)d_in[1];
    const int*   src    = (const int*)d_in[2];
    const int*   dst    = (const int*)d_in[3];
    const float* W_edge = (const float*)d_in[4];
    const float* W_ne   = (const float*)d_in[5];
    const float* b_ne   = (const float*)d_in[6];
    const float* W_self = (const float*)d_in[7];
    const float* b_self = (const float*)d_in[8];
    const float* eps    = (const float*)d_in[9];
    float* out = (float*)d_out;

    char* ws = (char*)d_ws;
    size_t off = 0;
    auto alloc = [&](size_t bytes) { void* p = ws + off; off = (off + bytes + 255) & ~(size_t)255; return p; };
    int*   cnt    = (int*)alloc((size_t)NNODES * 4);
    int*   cur    = (int*)alloc((size_t)NNODES * 4);
    int*   esd    = (int*)alloc((size_t)NEDGES * 4);
    short* escT   = (short*)alloc((size_t)NEDGES * EDGE_DIM * 2);
    short* nfB    = (short*)alloc((size_t)NNODES * IN_DIM * 2);
    short* WcatB  = (short*)alloc((size_t)OUT_DIM * KDIM * 2);
    short* WselfB = (short*)alloc((size_t)OUT_DIM * IN_DIM * 2);
    size_t need = off;

    if (ws_size >= need) {
        hipMemsetAsync(cnt, 0, (size_t)NNODES * 4, stream);
        hipMemsetAsync(out, 0, (size_t)NNODES * OUT_DIM * sizeof(float), stream);
        prep_kernel<<<1024, 256, 0, stream>>>(nfeat, dst, W_edge, W_ne, W_self,
                                              cnt, nfB, WcatB, WselfB);
        scan_kernel<<<1, 1024, 0, stream>>>(cnt, cur);
        scatter_kernel<<<(NEDGES + 255) / 256, 256, 0, stream>>>(
            src, dst, etype, cur, esd, escT);
        edge_kernel<<<EG, 256, 0, stream>>>(nfB, escT, esd, b_ne, WcatB, out);
        node_kernel<<<(NNODES + 63) / 64, 256, 0, stream>>>(nfB, b_self, eps,
                                                            WselfB, out);
    } else {
        short* WcatB2  = (short*)d_ws;
        short* WselfB2 = WcatB2 + (size_t)OUT_DIM * KDIM;
        hipMemsetAsync(out, 0, (size_t)NNODES * 128 * sizeof(float), stream);
        prep_w<<<144, 256, 0, stream>>>(W_edge, W_ne, W_self, WcatB2, WselfB2);
        edge_direct<<<NEDGES / 64, 256, 0, stream>>>(nfeat, etype, src, dst,
                                                     b_ne, WcatB2, out);
        node_direct<<<(NNODES + 63) / 64, 256, 0, stream>>>(nfeat, b_self, eps,
                                                            WselfB2, out);
    }
}

// Round 6
// 361.722 us; speedup vs baseline: 1.1859x; 1.1859x over previous
//
#include <hip/hip_runtime.h>
#include <hip/hip_bf16.h>

#define NNODES 50000
#define NEDGES 800000
#define IN_DIM 128
#define EDGE_DIM 32
#define OUT_DIM 128
#define KDIM 160          // IN_DIM + EDGE_DIM
#define A_STRIDE 168      // 160 + 8 pad, 16B aligned rows
#define NS 136            // 128 + 8 pad for node kernel
#define MT_STRIDE 72      // col-major m-tile: 72 shorts = 144 B (16B-aligned rows)
#define NT (NEDGES / 64)  // 12500 edge tiles
#define EG 768            // edge grid: 3 blocks/CU, strided tile assignment
#define NSCB 49           // scan blocks: 49*1024 >= 50000

typedef __attribute__((ext_vector_type(8))) short short8;
typedef __attribute__((ext_vector_type(4))) short short4v;
typedef __attribute__((ext_vector_type(4))) float floatx4;

__device__ __forceinline__ short f2bf(float f) {
    union { float f; unsigned u; } v; v.f = f;
    unsigned r = (v.u + 0x7FFFu + ((v.u >> 16) & 1u)) >> 16;  // RNE
    return (short)r;
}

__device__ __forceinline__ void store_bf4(short* p, floatx4 v) {
    short4v s;
    s.x = f2bf(v.x); s.y = f2bf(v.y); s.z = f2bf(v.z); s.w = f2bf(v.w);
    *(short4v*)p = s;
}

__device__ __forceinline__ void store_bf8(short* p, floatx4 a, floatx4 b) {
    short8 s;
    s[0] = f2bf(a.x); s[1] = f2bf(a.y); s[2] = f2bf(a.z); s[3] = f2bf(a.w);
    s[4] = f2bf(b.x); s[5] = f2bf(b.y); s[6] = f2bf(b.z); s[7] = f2bf(b.w);
    *(short8*)p = s;
}

#define MFMA8(ACC, A0, A1, B0, B1, B2, B3)                                        \
    ACC[0][0] = __builtin_amdgcn_mfma_f32_16x16x32_bf16(A0, B0, ACC[0][0], 0, 0, 0); \
    ACC[0][1] = __builtin_amdgcn_mfma_f32_16x16x32_bf16(A0, B1, ACC[0][1], 0, 0, 0); \
    ACC[0][2] = __builtin_amdgcn_mfma_f32_16x16x32_bf16(A0, B2, ACC[0][2], 0, 0, 0); \
    ACC[0][3] = __builtin_amdgcn_mfma_f32_16x16x32_bf16(A0, B3, ACC[0][3], 0, 0, 0); \
    ACC[1][0] = __builtin_amdgcn_mfma_f32_16x16x32_bf16(A1, B0, ACC[1][0], 0, 0, 0); \
    ACC[1][1] = __builtin_amdgcn_mfma_f32_16x16x32_bf16(A1, B1, ACC[1][1], 0, 0, 0); \
    ACC[1][2] = __builtin_amdgcn_mfma_f32_16x16x32_bf16(A1, B2, ACC[1][2], 0, 0, 0); \
    ACC[1][3] = __builtin_amdgcn_mfma_f32_16x16x32_bf16(A1, B3, ACC[1][3], 0, 0, 0);

// ---------------------------------------------------------------------------
// Prep: nfeat -> bf16 table, folded weights, AND dst histogram.
// (cnt and out pre-zeroed by hipMemsetAsync before this kernel.)
// ---------------------------------------------------------------------------
__global__ __launch_bounds__(256) void prep_kernel(
    const float* __restrict__ nfeat, const int* __restrict__ dst,
    const float* __restrict__ W_edge, const float* __restrict__ W_ne,
    const float* __restrict__ W_self,
    int* __restrict__ cnt, short* __restrict__ nfB,
    short* __restrict__ WcatB, short* __restrict__ WselfB)
{
    int gid = blockIdx.x * 256 + threadIdx.x;
    int GS = gridDim.x * 256;
    for (int i = gid; i < NNODES * IN_DIM / 8; i += GS) {
        floatx4 a = ((const floatx4*)nfeat)[2 * i];
        floatx4 b = ((const floatx4*)nfeat)[2 * i + 1];
        store_bf8(nfB + 8 * i, a, b);
    }
    for (int idx = gid; idx < OUT_DIM * KDIM + OUT_DIM * IN_DIM; idx += GS) {
        if (idx < OUT_DIM * KDIM) {
            int n = idx / KDIM, k = idx - n * KDIM;
            float val;
            if (k < IN_DIM) {
                val = W_ne[n * 256 + k];
            } else {
                int j = k - IN_DIM;
                float s = 0.f;
                for (int kk = 0; kk < 128; ++kk)
                    s += W_ne[n * 256 + 128 + kk] * W_edge[kk * 32 + j];
                val = s;
            }
            WcatB[idx] = f2bf(val);
        } else {
            int s = idx - OUT_DIM * KDIM;
            WselfB[s] = f2bf(W_self[s]);
        }
    }
    for (int e = gid; e < NEDGES; e += GS)
        atomicAdd(&cnt[dst[e]], 1);
}

// ---------------------------------------------------------------------------
// Parallel counting-sort scan (replaces 76 µs single-block scan):
//   scan_part : 49 blocks x 256 thr, int4/thread -> block sums
//   scan_mid  : 1 block x 64 thr, exclusive scan of 49 block sums
//   scan_write: 49 blocks x 256 thr, in-block exclusive scan + boff -> cur
// ---------------------------------------------------------------------------
__global__ __launch_bounds__(256) void scan_part(const int* __restrict__ cnt,
                                                 int* __restrict__ bsum) {
    __shared__ int red[256];
    int b = blockIdx.x, t = threadIdx.x;
    int idx = b * 1024 + t * 4;
    int4 v = {0, 0, 0, 0};
    if (idx < NNODES) v = *(const int4*)(cnt + idx);   // NNODES % 4 == 0
    red[t] = v.x + v.y + v.z + v.w;
    __syncthreads();
    for (int off = 128; off > 0; off >>= 1) {
        if (t < off) red[t] += red[t + off];
        __syncthreads();
    }
    if (t == 0) bsum[b] = red[0];
}

__global__ __launch_bounds__(64) void scan_mid(const int* __restrict__ bsum,
                                               int* __restrict__ boff) {
    __shared__ int a[64], b[64];
    int t = threadIdx.x;
    int v = (t < NSCB) ? bsum[t] : 0;
    a[t] = v;
    __syncthreads();
    int* in = a; int* out = b;
    for (int off = 1; off < 64; off <<= 1) {
        out[t] = in[t] + (t >= off ? in[t - off] : 0);
        __syncthreads();
        int* tmp = in; in = out; out = tmp;
    }
    if (t < NSCB) boff[t] = in[t] - v;     // exclusive
}

__global__ __launch_bounds__(256) void scan_write(const int* __restrict__ cnt,
                                                  const int* __restrict__ boff,
                                                  int* __restrict__ cur) {
    __shared__ int a[256], bb[256];
    int b = blockIdx.x, t = threadIdx.x;
    int idx = b * 1024 + t * 4;
    int4 v = {0, 0, 0, 0};
    if (idx < NNODES) v = *(const int4*)(cnt + idx);
    int s = v.x + v.y + v.z + v.w;
    a[t] = s;
    __syncthreads();
    int* in = a; int* out = bb;
    for (int off = 1; off < 256; off <<= 1) {
        out[t] = in[t] + (t >= off ? in[t - off] : 0);
        __syncthreads();
        int* tmp = in; in = out; out = tmp;
    }
    if (idx < NNODES) {
        int base = boff[b] + in[t] - s;    // exclusive prefix for this thread
        cur[idx] = base;     base += v.x;
        cur[idx + 1] = base; base += v.y;
        cur[idx + 2] = base; base += v.z;
        cur[idx + 3] = base;
    }
}

// Scatter: place packed (src|dst<<16) record at sorted position AND gather
// the edge's etype row (bf16-converted) to the same sorted position.
// etype read is SEQUENTIAL (by e); the 4B + 64B writes are random but
// fire-and-forget.
__global__ void scatter_kernel(const int* __restrict__ src,
                               const int* __restrict__ dst,
                               const float* __restrict__ etype,
                               int* __restrict__ cur,      // cursor (destroyed)
                               int* __restrict__ esd, short* __restrict__ escT) {
    int e = blockIdx.x * 256 + threadIdx.x;
    if (e < NEDGES) {
        int d = dst[e];
        int s = src[e];
        int pos = atomicAdd(&cur[d], 1);
        esd[pos] = (int)((unsigned)s | ((unsigned)d << 16));
        const floatx4* er = (const floatx4*)(etype + (size_t)e * 32);
        short* op = escT + (size_t)pos * 32;
        #pragma unroll
        for (int i = 0; i < 4; ++i) {
            floatx4 a = er[2 * i];
            floatx4 b = er[2 * i + 1];
            store_bf8(op + 8 * i, a, b);
        }
    }
}

// ---------------------------------------------------------------------------
// Edge kernel: persistent, strided tiles, 3 blocks/CU. R4 geometry (proven
// no-spill: always-live ~105 regs under (256,3)). Per-tile inputs are
// fully sorted+sequential: esd (4 B/edge) + escT (64 B/edge bf16 etype);
// only the nfB row gather remains random (L2/L3-absorbed).
// ---------------------------------------------------------------------------
__global__ __launch_bounds__(256, 3) void edge_kernel(
    const short* __restrict__ nfB, const short* __restrict__ escT,
    const int* __restrict__ esd, const float* __restrict__ b_ne,
    const short* __restrict__ WcatB, float* __restrict__ out)
{
    __shared__ short As[64 * A_STRIDE];            // 21504 B
    __shared__ unsigned short mT[128 * MT_STRIDE]; // 18432 B, col-major [o][el]
    __shared__ short dstL[2][64];                  // 256 B, double-buffered dsts

    const int tid = threadIdx.x;
    const int lane = tid & 63;
    const int w = tid >> 6;                        // wave id: cols w*32..w*32+31
    const int li = lane & 15, q = lane >> 4;

    // --- B-fragments to registers (once per block; L2-hot) ---
    short8 bf[2][5];
    #pragma unroll
    for (int ct = 0; ct < 2; ++ct)
        #pragma unroll
        for (int kk = 0; kk < 5; ++kk)
            bf[ct][kk] = *(const short8*)(WcatB +
                (size_t)(w * 32 + ct * 16 + li) * KDIM + kk * 32 + q * 8);

    float bias[2];
    #pragma unroll
    for (int ct = 0; ct < 2; ++ct) bias[ct] = b_ne[w * 32 + ct * 16 + li];

    const int ee = tid >> 2, ec = tid & 3;         // 4 threads per edge row

    short8 pv0, pv1, pv2, pv3;                     // prefetched nfB row quarter
    short8 pe;                                     // prefetched escT quarter
    int rsd = 0;                                   // record matching pv*/pe
    int psd = 0;                                   // record for t+2EG

    const int tA = blockIdx.x;                     // first tile (strided by EG)

    // --- prologue: stage tile tA; load heavy(tA+EG); psd = rec(tA+2EG) ---
    {
        int sd = esd[tA * 64 + ee];
        int s = sd & 0xFFFF;
        const short8* nr = (const short8*)(nfB + (size_t)s * 128);
        pv0 = nr[4 * ec]; pv1 = nr[4 * ec + 1];
        pv2 = nr[4 * ec + 2]; pv3 = nr[4 * ec + 3];
        pe = *(const short8*)(escT + (size_t)(tA * 64 + ee) * 32 + ec * 8);

        int tB = tA + EG;
        int sdB = 0;
        if (tB < NT) sdB = esd[tB * 64 + ee];

        short* ap = As + ee * A_STRIDE + 32 * ec;
        *(short8*)(ap)      = pv0;
        *(short8*)(ap + 8)  = pv1;
        *(short8*)(ap + 16) = pv2;
        *(short8*)(ap + 24) = pv3;
        *(short8*)(As + ee * A_STRIDE + IN_DIM + 8 * ec) = pe;
        if (ec == 0) dstL[0][ee] = (short)((unsigned)sd >> 16);

        if (tB < NT) {
            int sB = sdB & 0xFFFF;
            const short8* nrB = (const short8*)(nfB + (size_t)sB * 128);
            pv0 = nrB[4 * ec]; pv1 = nrB[4 * ec + 1];
            pv2 = nrB[4 * ec + 2]; pv3 = nrB[4 * ec + 3];
            pe = *(const short8*)(escT + (size_t)(tB * 64 + ee) * 32 + ec * 8);
            rsd = sdB;
            int tC = tB + EG;
            if (tC < NT) psd = esd[tC * 64 + ee];
        }
    }

    int it = 0;
    for (int t = tA; t < NT; t += EG, ++it) {
        const int cb = it & 1, nb = cb ^ 1;

        // sync1: As(t)/dstL(t) visible. lgkm-only: prefetch stays in flight.
        asm volatile("s_waitcnt lgkmcnt(0)" ::: "memory");
        __builtin_amdgcn_s_barrier();

        floatx4 acc[4][2];                         // [row-tile][col-tile]
        #pragma unroll
        for (int i = 0; i < 4; ++i)
            #pragma unroll
            for (int j = 0; j < 2; ++j)
                acc[i][j] = (floatx4){0.f, 0.f, 0.f, 0.f};

        __builtin_amdgcn_s_setprio(1);
        #pragma unroll
        for (int kk = 0; kk < 5; ++kk) {
            short8 a0 = *(const short8*)(As + (0 * 16 + li) * A_STRIDE + kk * 32 + q * 8);
            short8 a1 = *(const short8*)(As + (1 * 16 + li) * A_STRIDE + kk * 32 + q * 8);
            short8 a2 = *(const short8*)(As + (2 * 16 + li) * A_STRIDE + kk * 32 + q * 8);
            short8 a3 = *(const short8*)(As + (3 * 16 + li) * A_STRIDE + kk * 32 + q * 8);
            acc[0][0] = __builtin_amdgcn_mfma_f32_16x16x32_bf16(a0, bf[0][kk], acc[0][0], 0, 0, 0);
            acc[0][1] = __builtin_amdgcn_mfma_f32_16x16x32_bf16(a0, bf[1][kk], acc[0][1], 0, 0, 0);
            acc[1][0] = __builtin_amdgcn_mfma_f32_16x16x32_bf16(a1, bf[0][kk], acc[1][0], 0, 0, 0);
            acc[1][1] = __builtin_amdgcn_mfma_f32_16x16x32_bf16(a1, bf[1][kk], acc[1][1], 0, 0, 0);
            acc[2][0] = __builtin_amdgcn_mfma_f32_16x16x32_bf16(a2, bf[0][kk], acc[2][0], 0, 0, 0);
            acc[2][1] = __builtin_amdgcn_mfma_f32_16x16x32_bf16(a2, bf[1][kk], acc[2][1], 0, 0, 0);
            acc[3][0] = __builtin_amdgcn_mfma_f32_16x16x32_bf16(a3, bf[0][kk], acc[3][0], 0, 0, 0);
            acc[3][1] = __builtin_amdgcn_mfma_f32_16x16x32_bf16(a3, bf[1][kk], acc[3][1], 0, 0, 0);
        }
        __builtin_amdgcn_s_setprio(0);

        // --- relu+bias -> col-major mT; C/D: row = q*4+r, col = li ---
        #pragma unroll
        for (int rt = 0; rt < 4; ++rt) {
            #pragma unroll
            for (int ct = 0; ct < 2; ++ct) {
                floatx4 a = acc[rt][ct];
                short4v s;
                float v0 = a.x + bias[ct]; s.x = f2bf(v0 > 0.f ? v0 : 0.f);
                float v1 = a.y + bias[ct]; s.y = f2bf(v1 > 0.f ? v1 : 0.f);
                float v2 = a.z + bias[ct]; s.z = f2bf(v2 > 0.f ? v2 : 0.f);
                float v3 = a.w + bias[ct]; s.w = f2bf(v3 > 0.f ? v3 : 0.f);
                *(short4v*)((short*)mT + (w * 32 + ct * 16 + li) * MT_STRIDE
                            + rt * 16 + q * 4) = s;
            }
        }
        // sync2: mT(t) visible; all waves done reading As(t).
        asm volatile("s_waitcnt lgkmcnt(0)" ::: "memory");
        __builtin_amdgcn_s_barrier();

        // --- stage tile t+EG from regs; issue gathers for t+2EG ---
        {
            int tn = t + EG;
            if (tn < NT) {
                short* ap = As + ee * A_STRIDE + 32 * ec;
                *(short8*)(ap)      = pv0;
                *(short8*)(ap + 8)  = pv1;
                *(short8*)(ap + 16) = pv2;
                *(short8*)(ap + 24) = pv3;
                *(short8*)(As + ee * A_STRIDE + IN_DIM + 8 * ec) = pe;
                if (ec == 0) dstL[nb][ee] = (short)((unsigned)rsd >> 16);

                int sd2 = psd;
                int t2 = tn + EG;
                if (t2 < NT) {
                    int t3 = t2 + EG;
                    if (t3 < NT) psd = esd[t3 * 64 + ee];
                    int s2 = sd2 & 0xFFFF;
                    const short8* nr2 = (const short8*)(nfB + (size_t)s2 * 128);
                    pv0 = nr2[4 * ec]; pv1 = nr2[4 * ec + 1];
                    pv2 = nr2[4 * ec + 2]; pv3 = nr2[4 * ec + 3];
                    pe = *(const short8*)(escT + (size_t)(t2 * 64 + ee) * 32 + ec * 8);
                    rsd = sd2;
                }
            }
        }
        __builtin_amdgcn_sched_barrier(0);  // keep prefetch issue ahead of scan

        // --- per-column run-max; dsts from LDS broadcast, SCALAR control ---
        {
            int c = tid & 127, h = tid >> 7;
            int r0 = h * 32;
            unsigned mval[32];
            #pragma unroll
            for (int j = 0; j < 4; ++j) {
                short8 v = *(const short8*)((const short*)mT + c * MT_STRIDE
                                            + r0 + 8 * j);
                #pragma unroll
                for (int k = 0; k < 8; ++k)
                    mval[8 * j + k] = (unsigned short)v[k];
            }
            const short8* dls = (const short8*)(&dstL[cb][r0]);
            int curd = 0;
            unsigned best = 0;
            #pragma unroll
            for (int j = 0; j < 4; ++j) {
                short8 dv = dls[j];
                #pragma unroll
                for (int k = 0; k < 8; ++k) {
                    int r = 8 * j + k;
                    int d = __builtin_amdgcn_readfirstlane(
                        (int)(unsigned short)dv[k]);
                    if (r == 0) {
                        curd = d; best = mval[0];
                    } else if (d != curd) {
                        atomicMax((int*)out + (size_t)curd * 128 + c,
                                  (int)(best << 16));
                        curd = d; best = mval[r];
                    } else {
                        best = best > mval[r] ? best : mval[r];
                    }
                }
            }
            atomicMax((int*)out + (size_t)curd * 128 + c, (int)(best << 16));
        }
    }
}

// ---------------------------------------------------------------------------
// Node kernel (in-place): out = (1+eps)*out + nfeat @ W_self^T + b_self
// ---------------------------------------------------------------------------
__global__ __launch_bounds__(256) void node_kernel(
    const short* __restrict__ nfB, const float* __restrict__ b_self,
    const float* __restrict__ eps, const short* __restrict__ WselfB,
    float* __restrict__ out)
{
    __shared__ short As[64 * NS];
    __shared__ short Bs[128 * NS];
    const int tid = threadIdx.x;
    const int n0 = blockIdx.x * 64;

    {
        int r = tid >> 1, h = tid & 1;
        const short8* g = (const short8*)(WselfB + r * 128 + h * 64);
        short* l = Bs + r * NS + h * 64;
        #pragma unroll
        for (int c = 0; c < 8; ++c)
            *(short8*)(l + 8 * c) = g[c];
    }
    {
        int r = tid >> 2, c = tid & 3;
        int n = n0 + r;
        short* ap = As + r * NS + 32 * c;
        if (n < NNODES) {
            const short8* nr = (const short8*)(nfB + (size_t)n * 128);
            #pragma unroll
            for (int j = 0; j < 4; ++j)
                *(short8*)(ap + 8 * j) = nr[4 * c + j];
        } else {
            #pragma unroll
            for (int j = 0; j < 4; ++j)
                *(short8*)(ap + 8 * j) = (short8){0,0,0,0,0,0,0,0};
        }
    }
    __syncthreads();

    const int lane = tid & 63;
    const int w = tid >> 6;
    const int et = w & 1;
    const int nh = w >> 1;
    const int li = lane & 15, q = lane >> 4;

    floatx4 acc[2][4];
    #pragma unroll
    for (int i = 0; i < 2; ++i)
        #pragma unroll
        for (int j = 0; j < 4; ++j)
            acc[i][j] = (floatx4){0.f, 0.f, 0.f, 0.f};

    const short* Ab = As + (et * 32 + li) * NS + q * 8;
    const short* Bb = Bs + (nh * 64 + li) * NS + q * 8;
    #pragma unroll
    for (int kk = 0; kk < 4; ++kk) {
        short8 a0 = *(const short8*)(Ab + kk * 32);
        short8 a1 = *(const short8*)(Ab + 16 * NS + kk * 32);
        short8 b0 = *(const short8*)(Bb + kk * 32);
        short8 b1 = *(const short8*)(Bb + 16 * NS + kk * 32);
        short8 b2 = *(const short8*)(Bb + 32 * NS + kk * 32);
        short8 b3 = *(const short8*)(Bb + 48 * NS + kk * 32);
        MFMA8(acc, a0, a1, b0, b1, b2, b3)
    }

    const float epsv = 1.0f + eps[0];
    #pragma unroll
    for (int ta = 0; ta < 2; ++ta) {
        #pragma unroll
        for (int r = 0; r < 4; ++r) {
            int n = n0 + et * 32 + ta * 16 + q * 4 + r;
            if (n < NNODES) {
                #pragma unroll
                for (int tb = 0; tb < 4; ++tb) {
                    int o = nh * 64 + tb * 16 + li;
                    float v = acc[ta][tb][r] + b_self[o]
                            + epsv * out[(size_t)n * 128 + o];
                    out[(size_t)n * 128 + o] = v;
                }
            }
        }
    }
}

// ===========================================================================
// Fallback kernels (direct path) — used only if ws_size too small.
// ===========================================================================
__global__ void prep_w(const float* __restrict__ W_edge,
                       const float* __restrict__ W_ne,
                       const float* __restrict__ W_self,
                       short* __restrict__ WcatB, short* __restrict__ WselfB)
{
    int idx = blockIdx.x * 256 + threadIdx.x;
    if (idx < OUT_DIM * KDIM) {
        int n = idx / KDIM, k = idx - n * KDIM;
        float val;
        if (k < IN_DIM) {
            val = W_ne[n * 256 + k];
        } else {
            int j = k - IN_DIM;
            float s = 0.f;
            for (int kk = 0; kk < 128; ++kk)
                s += W_ne[n * 256 + 128 + kk] * W_edge[kk * 32 + j];
            val = s;
        }
        WcatB[idx] = f2bf(val);
    } else if (idx < OUT_DIM * KDIM + OUT_DIM * IN_DIM) {
        int s = idx - OUT_DIM * KDIM;
        WselfB[s] = f2bf(W_self[s]);
    }
}

__global__ __launch_bounds__(256) void edge_direct(
    const float* __restrict__ nfeat, const float* __restrict__ etype,
    const int* __restrict__ src, const int* __restrict__ dst,
    const float* __restrict__ b_ne, const short* __restrict__ WcatB,
    float* __restrict__ out)
{
    __shared__ short As[64 * A_STRIDE];
    __shared__ short Bs[128 * A_STRIDE];
    const int tid = threadIdx.x;
    const int e0 = blockIdx.x * 64;
    {
        int r = tid >> 1, h = tid & 1;
        const short8* g = (const short8*)(WcatB + r * KDIM + h * 80);
        short* l = Bs + r * A_STRIDE + h * 80;
        #pragma unroll
        for (int c = 0; c < 10; ++c) *(short8*)(l + 8 * c) = g[c];
    }
    {
        const floatx4* ge = (const floatx4*)(etype + (size_t)e0 * 32);
        #pragma unroll
        for (int i = 0; i < 2; ++i) {
            int f = tid + i * 256;
            int e = f >> 3, c = f & 7;
            store_bf4(As + e * A_STRIDE + IN_DIM + 4 * c, ge[f]);
        }
    }
    {
        int g = tid & 15, eo = tid >> 4;
        #pragma unroll
        for (int p = 0; p < 4; ++p) {
            int e = eo + p * 16;
            int s = src[e0 + e];
            const floatx4* row = (const floatx4*)(nfeat + (size_t)s * 128);
            floatx4 v0 = row[g];
            floatx4 v1 = row[g + 16];
            store_bf4(As + e * A_STRIDE + 4 * g, v0);
            store_bf4(As + e * A_STRIDE + 64 + 4 * g, v1);
        }
    }
    __syncthreads();
    const int lane = tid & 63;
    const int w = tid >> 6;
    const int et = w & 1, nh = w >> 1;
    const int li = lane & 15, q = lane >> 4;
    floatx4 acc[2][4];
    #pragma unroll
    for (int i = 0; i < 2; ++i)
        #pragma unroll
        for (int j = 0; j < 4; ++j)
            acc[i][j] = (floatx4){0.f, 0.f, 0.f, 0.f};
    const short* Ab = As + (et * 32 + li) * A_STRIDE + q * 8;
    const short* Bb = Bs + (nh * 64 + li) * A_STRIDE + q * 8;
    #pragma unroll
    for (int kk = 0; kk < 5; ++kk) {
        short8 a0 = *(const short8*)(Ab + kk * 32);
        short8 a1 = *(const short8*)(Ab + 16 * A_STRIDE + kk * 32);
        short8 b0 = *(const short8*)(Bb + kk * 32);
        short8 b1 = *(const short8*)(Bb + 16 * A_STRIDE + kk * 32);
        short8 b2 = *(const short8*)(Bb + 32 * A_STRIDE + kk * 32);
        short8 b3 = *(const short8*)(Bb + 48 * A_STRIDE + kk * 32);
        MFMA8(acc, a0, a1, b0, b1, b2, b3)
    }
    #pragma unroll
    for (int ta = 0; ta < 2; ++ta) {
        #pragma unroll
        for (int r = 0; r < 4; ++r) {
            int el = et * 32 + ta * 16 + q * 4 + r;
            int d = dst[e0 + el];
            int* nrow = (int*)out + (size_t)d * 128;
            #pragma unroll
            for (int tb = 0; tb < 4; ++tb) {
                int o = nh * 64 + tb * 16 + li;
                float v = acc[ta][tb][r] + b_ne[o];
                v = v > 0.f ? v : 0.f;
                atomicMax(nrow + o, __float_as_int(v));
            }
        }
    }
}

__global__ __launch_bounds__(256) void node_direct(
    const float* __restrict__ nfeat, const float* __restrict__ b_self,
    const float* __restrict__ eps, const short* __restrict__ WselfB,
    float* __restrict__ out)
{
    __shared__ short As[64 * NS];
    __shared__ short Bs[128 * NS];
    const int tid = threadIdx.x;
    const int n0 = blockIdx.x * 64;
    {
        int r = tid >> 1, h = tid & 1;
        const short8* g = (const short8*)(WselfB + r * 128 + h * 64);
        short* l = Bs + r * NS + h * 64;
        #pragma unroll
        for (int c = 0; c < 8; ++c) *(short8*)(l + 8 * c) = g[c];
    }
    {
        int r = tid >> 2, fi = tid & 3;
        int n = n0 + r;
        if (n < NNODES) {
            const floatx4* row = (const floatx4*)(nfeat + (size_t)n * 128);
            #pragma unroll
            for (int p = 0; p < 8; ++p) {
                int f = fi + 4 * p;
                store_bf4(As + r * NS + 4 * f, row[f]);
            }
        } else {
            #pragma unroll
            for (int p = 0; p < 8; ++p) {
                int f = fi + 4 * p;
                *(short4v*)(As + r * NS + 4 * f) = (short4v){0, 0, 0, 0};
            }
        }
    }
    __syncthreads();
    const int lane = tid & 63;
    const int w = tid >> 6;
    const int et = w & 1, nh = w >> 1;
    const int li = lane & 15, q = lane >> 4;
    floatx4 acc[2][4];
    #pragma unroll
    for (int i = 0; i < 2; ++i)
        #pragma unroll
        for (int j = 0; j < 4; ++j)
            acc[i][j] = (floatx4){0.f, 0.f, 0.f, 0.f};
    const short* Ab = As + (et * 32 + li) * NS + q * 8;
    const short* Bb = Bs + (nh * 64 + li) * NS + q * 8;
    #pragma unroll
    for (int kk = 0; kk < 4; ++kk) {
        short8 a0 = *(const short8*)(Ab + kk * 32);
        short8 a1 = *(const short8*)(Ab + 16 * NS + kk * 32);
        short8 b0 = *(const short8*)(Bb + kk * 32);
        short8 b1 = *(const short8*)(Bb + 16 * NS + kk * 32);
        short8 b2 = *(const short8*)(Bb + 32 * NS + kk * 32);
        short8 b3 = *(const short8*)(Bb + 48 * NS + kk * 32);
        MFMA8(acc, a0, a1, b0, b1, b2, b3)
    }
    const float epsv = 1.0f + eps[0];
    #pragma unroll
    for (int ta = 0; ta < 2; ++ta) {
        #pragma unroll
        for (int r = 0; r < 4; ++r) {
            int n = n0 + et * 32 + ta * 16 + q * 4 + r;
            if (n < NNODES) {
                #pragma unroll
                for (int tb = 0; tb < 4; ++tb) {
                    int o = nh * 64 + tb * 16 + li;
                    float v = acc[ta][tb][r] + b_self[o]
                            + epsv * out[(size_t)n * 128 + o];
                    out[(size_t)n * 128 + o] = v;
                }
            }
        }
    }
}

// ---------------------------------------------------------------------------
extern "C" void kernel_launch(void* const* d_in, const int* in_sizes, int n_in,
                              void* d_out, int out_size, void* d_ws, size_t ws_size,
                              hipStream_t stream) {
    const float* nfeat  = (const float*)d_in[0];
    const float* etype  = (const float*)d_in[1];
    const int*   src    = (const int*)d_in[2];
    const int*   dst    = (const int*)d_in[3];
    const float* W_edge = (const float*)d_in[4];
    const float* W_ne   = (const float*)d_in[5];
    const float* b_ne   = (const float*)d_in[6];
    const float* W_self = (const float*)d_in[7];
    const float* b_self = (const float*)d_in[8];
    const float* eps    = (const float*)d_in[9];
    float* out = (float*)d_out;

    char* ws = (char*)d_ws;
    size_t off = 0;
    auto alloc = [&](size_t bytes) { void* p = ws + off; off = (off + bytes + 255) & ~(size_t)255; return p; };
    int*   cnt    = (int*)alloc((size_t)NNODES * 4);
    int*   cur    = (int*)alloc((size_t)NNODES * 4);
    int*   esd    = (int*)alloc((size_t)NEDGES * 4);
    short* escT   = (short*)alloc((size_t)NEDGES * EDGE_DIM * 2);
    short* nfB    = (short*)alloc((size_t)NNODES * IN_DIM * 2);
    short* WcatB  = (short*)alloc((size_t)OUT_DIM * KDIM * 2);
    short* WselfB = (short*)alloc((size_t)OUT_DIM * IN_DIM * 2);
    int*   bsum   = (int*)alloc((size_t)NSCB * 4);
    int*   boff   = (int*)alloc((size_t)NSCB * 4);
    size_t need = off;

    if (ws_size >= need) {
        hipMemsetAsync(cnt, 0, (size_t)NNODES * 4, stream);
        hipMemsetAsync(out, 0, (size_t)NNODES * OUT_DIM * sizeof(float), stream);
        prep_kernel<<<1024, 256, 0, stream>>>(nfeat, dst, W_edge, W_ne, W_self,
                                              cnt, nfB, WcatB, WselfB);
        scan_part<<<NSCB, 256, 0, stream>>>(cnt, bsum);
        scan_mid<<<1, 64, 0, stream>>>(bsum, boff);
        scan_write<<<NSCB, 256, 0, stream>>>(cnt, boff, cur);
        scatter_kernel<<<(NEDGES + 255) / 256, 256, 0, stream>>>(
            src, dst, etype, cur, esd, escT);
        edge_kernel<<<EG, 256, 0, stream>>>(nfB, escT, esd, b_ne, WcatB, out);
        node_kernel<<<(NNODES + 63) / 64, 256, 0, stream>>>(nfB, b_self, eps,
                                                            WselfB, out);
    } else {
        short* WcatB2  = (short*)d_ws;
        short* WselfB2 = WcatB2 + (size_t)OUT_DIM * KDIM;
        hipMemsetAsync(out, 0, (size_t)NNODES * 128 * sizeof(float), stream);
        prep_w<<<144, 256, 0, stream>>>(W_edge, W_ne, W_self, WcatB2, WselfB2);
        edge_direct<<<NEDGES / 64, 256, 0, stream>>>(nfeat, etype, src, dst,
                                                     b_ne, WcatB2, out);
        node_direct<<<(NNODES + 63) / 64, 256, 0, stream>>>(nfeat, b_self, eps,
                                                            WselfB2, out);
    }
}

// Round 7
// 351.697 us; speedup vs baseline: 1.2197x; 1.0285x over previous
//
#include <hip/hip_runtime.h>
#include <hip/hip_bf16.h>

#define NNODES 50000
#define NEDGES 800000
#define IN_DIM 128
#define EDGE_DIM 32
#define OUT_DIM 128
#define KDIM 160          // IN_DIM + EDGE_DIM
#define A_STRIDE 168      // 160 + 8 pad, 16B aligned rows
#define NS 136            // 128 + 8 pad for node kernel
#define MT_STRIDE 72      // col-major m-tile: 72 shorts = 144 B (16B-aligned rows)
#define NT (NEDGES / 64)  // 12500 edge tiles
#define EG 768            // edge grid: 3 blocks/CU, strided tile assignment
#define NSCB 49           // scan blocks: 49*1024 >= 50000

typedef __attribute__((ext_vector_type(8))) short short8;
typedef __attribute__((ext_vector_type(4))) short short4v;
typedef __attribute__((ext_vector_type(4))) float floatx4;

__device__ __forceinline__ short f2bf(float f) {
    union { float f; unsigned u; } v; v.f = f;
    unsigned r = (v.u + 0x7FFFu + ((v.u >> 16) & 1u)) >> 16;  // RNE
    return (short)r;
}

__device__ __forceinline__ void store_bf4(short* p, floatx4 v) {
    short4v s;
    s.x = f2bf(v.x); s.y = f2bf(v.y); s.z = f2bf(v.z); s.w = f2bf(v.w);
    *(short4v*)p = s;
}

__device__ __forceinline__ void store_bf8(short* p, floatx4 a, floatx4 b) {
    short8 s;
    s[0] = f2bf(a.x); s[1] = f2bf(a.y); s[2] = f2bf(a.z); s[3] = f2bf(a.w);
    s[4] = f2bf(b.x); s[5] = f2bf(b.y); s[6] = f2bf(b.z); s[7] = f2bf(b.w);
    *(short8*)p = s;
}

#define MFMA8(ACC, A0, A1, B0, B1, B2, B3)                                        \
    ACC[0][0] = __builtin_amdgcn_mfma_f32_16x16x32_bf16(A0, B0, ACC[0][0], 0, 0, 0); \
    ACC[0][1] = __builtin_amdgcn_mfma_f32_16x16x32_bf16(A0, B1, ACC[0][1], 0, 0, 0); \
    ACC[0][2] = __builtin_amdgcn_mfma_f32_16x16x32_bf16(A0, B2, ACC[0][2], 0, 0, 0); \
    ACC[0][3] = __builtin_amdgcn_mfma_f32_16x16x32_bf16(A0, B3, ACC[0][3], 0, 0, 0); \
    ACC[1][0] = __builtin_amdgcn_mfma_f32_16x16x32_bf16(A1, B0, ACC[1][0], 0, 0, 0); \
    ACC[1][1] = __builtin_amdgcn_mfma_f32_16x16x32_bf16(A1, B1, ACC[1][1], 0, 0, 0); \
    ACC[1][2] = __builtin_amdgcn_mfma_f32_16x16x32_bf16(A1, B2, ACC[1][2], 0, 0, 0); \
    ACC[1][3] = __builtin_amdgcn_mfma_f32_16x16x32_bf16(A1, B3, ACC[1][3], 0, 0, 0);

// ---------------------------------------------------------------------------
// Prep: nfeat -> bf16 table, folded weights, AND dst histogram.
// (cnt and out pre-zeroed by hipMemsetAsync before this kernel.)
// ---------------------------------------------------------------------------
__global__ __launch_bounds__(256) void prep_kernel(
    const float* __restrict__ nfeat, const int* __restrict__ dst,
    const float* __restrict__ W_edge, const float* __restrict__ W_ne,
    const float* __restrict__ W_self,
    int* __restrict__ cnt, short* __restrict__ nfB,
    short* __restrict__ WcatB, short* __restrict__ WselfB)
{
    int gid = blockIdx.x * 256 + threadIdx.x;
    int GS = gridDim.x * 256;
    for (int i = gid; i < NNODES * IN_DIM / 8; i += GS) {
        floatx4 a = ((const floatx4*)nfeat)[2 * i];
        floatx4 b = ((const floatx4*)nfeat)[2 * i + 1];
        store_bf8(nfB + 8 * i, a, b);
    }
    for (int idx = gid; idx < OUT_DIM * KDIM + OUT_DIM * IN_DIM; idx += GS) {
        if (idx < OUT_DIM * KDIM) {
            int n = idx / KDIM, k = idx - n * KDIM;
            float val;
            if (k < IN_DIM) {
                val = W_ne[n * 256 + k];
            } else {
                int j = k - IN_DIM;
                float s = 0.f;
                for (int kk = 0; kk < 128; ++kk)
                    s += W_ne[n * 256 + 128 + kk] * W_edge[kk * 32 + j];
                val = s;
            }
            WcatB[idx] = f2bf(val);
        } else {
            int s = idx - OUT_DIM * KDIM;
            WselfB[s] = f2bf(W_self[s]);
        }
    }
    for (int e = gid; e < NEDGES; e += GS)
        atomicAdd(&cnt[dst[e]], 1);
}

// ---------------------------------------------------------------------------
// Parallel counting-sort scan:
//   scan_part : 49 blocks x 256 thr, int4/thread -> block sums
//   scan_mid  : 1 block x 64 thr, exclusive scan of 49 block sums
//   scan_write: 49 blocks x 256 thr, in-block exclusive scan + boff -> cur
// ---------------------------------------------------------------------------
__global__ __launch_bounds__(256) void scan_part(const int* __restrict__ cnt,
                                                 int* __restrict__ bsum) {
    __shared__ int red[256];
    int b = blockIdx.x, t = threadIdx.x;
    int idx = b * 1024 + t * 4;
    int4 v = {0, 0, 0, 0};
    if (idx < NNODES) v = *(const int4*)(cnt + idx);   // NNODES % 4 == 0
    red[t] = v.x + v.y + v.z + v.w;
    __syncthreads();
    for (int off = 128; off > 0; off >>= 1) {
        if (t < off) red[t] += red[t + off];
        __syncthreads();
    }
    if (t == 0) bsum[b] = red[0];
}

__global__ __launch_bounds__(64) void scan_mid(const int* __restrict__ bsum,
                                               int* __restrict__ boff) {
    __shared__ int a[64], b[64];
    int t = threadIdx.x;
    int v = (t < NSCB) ? bsum[t] : 0;
    a[t] = v;
    __syncthreads();
    int* in = a; int* out = b;
    for (int off = 1; off < 64; off <<= 1) {
        out[t] = in[t] + (t >= off ? in[t - off] : 0);
        __syncthreads();
        int* tmp = in; in = out; out = tmp;
    }
    if (t < NSCB) boff[t] = in[t] - v;     // exclusive
}

__global__ __launch_bounds__(256) void scan_write(const int* __restrict__ cnt,
                                                  const int* __restrict__ boff,
                                                  int* __restrict__ cur) {
    __shared__ int a[256], bb[256];
    int b = blockIdx.x, t = threadIdx.x;
    int idx = b * 1024 + t * 4;
    int4 v = {0, 0, 0, 0};
    if (idx < NNODES) v = *(const int4*)(cnt + idx);
    int s = v.x + v.y + v.z + v.w;
    a[t] = s;
    __syncthreads();
    int* in = a; int* out = bb;
    for (int off = 1; off < 256; off <<= 1) {
        out[t] = in[t] + (t >= off ? in[t - off] : 0);
        __syncthreads();
        int* tmp = in; in = out; out = tmp;
    }
    if (idx < NNODES) {
        int base = boff[b] + in[t] - s;    // exclusive prefix for this thread
        cur[idx] = base;     base += v.x;
        cur[idx + 1] = base; base += v.y;
        cur[idx + 2] = base; base += v.z;
        cur[idx + 3] = base;
    }
}

// ---------------------------------------------------------------------------
// Scatter, 8-lanes-per-edge cooperative: a wave handles 8 consecutive edges.
// Group leaders (lane%8==0) do the atomicAdd in ONE exec-masked instruction
// (8 positions per vmem op); __shfl broadcasts pos within each group. Each
// lane reads one floatx4 of the etype row -> wave reads 8 rows = 1 KB fully
// coalesced per load instr (was 64 lines/instr); each group stores 64 B
// contiguous bf16. Removes the 8x issue overhead and the 5-store serial
// chain behind each atomic return.
// ---------------------------------------------------------------------------
__global__ __launch_bounds__(256) void scatter_kernel(
    const int* __restrict__ src, const int* __restrict__ dst,
    const float* __restrict__ etype,
    int* __restrict__ cur,      // cursor (destroyed)
    int* __restrict__ esd, short* __restrict__ escT) {
    const int tid = threadIdx.x;
    const int lane = tid & 63;
    const int g = lane & 7;                       // lane within 8-lane group
    const int ldr = lane & ~7;                    // group-leader lane id
    const int grp = tid >> 3;                     // group id within block (0..31)
    const int GS = gridDim.x * 32;
    for (int e = blockIdx.x * 32 + grp; e < NEDGES; e += GS) {
        int pos = 0;
        if (g == 0) {
            int d = dst[e];
            int s = src[e];
            pos = atomicAdd(&cur[d], 1);
            esd[pos] = (int)((unsigned)s | ((unsigned)d << 16));
        }
        pos = __shfl(pos, ldr);                   // broadcast within group
        floatx4 v = ((const floatx4*)(etype + (size_t)e * 32))[g];
        store_bf4(escT + (size_t)pos * 32 + g * 4, v);
    }
}

// ---------------------------------------------------------------------------
// Edge kernel: persistent, strided tiles, 3 blocks/CU. R4 geometry (proven
// no-spill: always-live ~105 regs under (256,3)). Per-tile inputs are
// fully sorted+sequential: esd (4 B/edge) + escT (64 B/edge bf16 etype);
// only the nfB row gather remains random (L2/L3-absorbed).
// ---------------------------------------------------------------------------
__global__ __launch_bounds__(256, 3) void edge_kernel(
    const short* __restrict__ nfB, const short* __restrict__ escT,
    const int* __restrict__ esd, const float* __restrict__ b_ne,
    const short* __restrict__ WcatB, float* __restrict__ out)
{
    __shared__ short As[64 * A_STRIDE];            // 21504 B
    __shared__ unsigned short mT[128 * MT_STRIDE]; // 18432 B, col-major [o][el]
    __shared__ short dstL[2][64];                  // 256 B, double-buffered dsts

    const int tid = threadIdx.x;
    const int lane = tid & 63;
    const int w = tid >> 6;                        // wave id: cols w*32..w*32+31
    const int li = lane & 15, q = lane >> 4;

    // --- B-fragments to registers (once per block; L2-hot) ---
    short8 bf[2][5];
    #pragma unroll
    for (int ct = 0; ct < 2; ++ct)
        #pragma unroll
        for (int kk = 0; kk < 5; ++kk)
            bf[ct][kk] = *(const short8*)(WcatB +
                (size_t)(w * 32 + ct * 16 + li) * KDIM + kk * 32 + q * 8);

    float bias[2];
    #pragma unroll
    for (int ct = 0; ct < 2; ++ct) bias[ct] = b_ne[w * 32 + ct * 16 + li];

    const int ee = tid >> 2, ec = tid & 3;         // 4 threads per edge row

    short8 pv0, pv1, pv2, pv3;                     // prefetched nfB row quarter
    short8 pe;                                     // prefetched escT quarter
    int rsd = 0;                                   // record matching pv*/pe
    int psd = 0;                                   // record for t+2EG

    const int tA = blockIdx.x;                     // first tile (strided by EG)

    // --- prologue: stage tile tA; load heavy(tA+EG); psd = rec(tA+2EG) ---
    {
        int sd = esd[tA * 64 + ee];
        int s = sd & 0xFFFF;
        const short8* nr = (const short8*)(nfB + (size_t)s * 128);
        pv0 = nr[4 * ec]; pv1 = nr[4 * ec + 1];
        pv2 = nr[4 * ec + 2]; pv3 = nr[4 * ec + 3];
        pe = *(const short8*)(escT + (size_t)(tA * 64 + ee) * 32 + ec * 8);

        int tB = tA + EG;
        int sdB = 0;
        if (tB < NT) sdB = esd[tB * 64 + ee];

        short* ap = As + ee * A_STRIDE + 32 * ec;
        *(short8*)(ap)      = pv0;
        *(short8*)(ap + 8)  = pv1;
        *(short8*)(ap + 16) = pv2;
        *(short8*)(ap + 24) = pv3;
        *(short8*)(As + ee * A_STRIDE + IN_DIM + 8 * ec) = pe;
        if (ec == 0) dstL[0][ee] = (short)((unsigned)sd >> 16);

        if (tB < NT) {
            int sB = sdB & 0xFFFF;
            const short8* nrB = (const short8*)(nfB + (size_t)sB * 128);
            pv0 = nrB[4 * ec]; pv1 = nrB[4 * ec + 1];
            pv2 = nrB[4 * ec + 2]; pv3 = nrB[4 * ec + 3];
            pe = *(const short8*)(escT + (size_t)(tB * 64 + ee) * 32 + ec * 8);
            rsd = sdB;
            int tC = tB + EG;
            if (tC < NT) psd = esd[tC * 64 + ee];
        }
    }

    int it = 0;
    for (int t = tA; t < NT; t += EG, ++it) {
        const int cb = it & 1, nb = cb ^ 1;

        // sync1: As(t)/dstL(t) visible. lgkm-only: prefetch stays in flight.
        asm volatile("s_waitcnt lgkmcnt(0)" ::: "memory");
        __builtin_amdgcn_s_barrier();

        floatx4 acc[4][2];                         // [row-tile][col-tile]
        #pragma unroll
        for (int i = 0; i < 4; ++i)
            #pragma unroll
            for (int j = 0; j < 2; ++j)
                acc[i][j] = (floatx4){0.f, 0.f, 0.f, 0.f};

        __builtin_amdgcn_s_setprio(1);
        #pragma unroll
        for (int kk = 0; kk < 5; ++kk) {
            short8 a0 = *(const short8*)(As + (0 * 16 + li) * A_STRIDE + kk * 32 + q * 8);
            short8 a1 = *(const short8*)(As + (1 * 16 + li) * A_STRIDE + kk * 32 + q * 8);
            short8 a2 = *(const short8*)(As + (2 * 16 + li) * A_STRIDE + kk * 32 + q * 8);
            short8 a3 = *(const short8*)(As + (3 * 16 + li) * A_STRIDE + kk * 32 + q * 8);
            acc[0][0] = __builtin_amdgcn_mfma_f32_16x16x32_bf16(a0, bf[0][kk], acc[0][0], 0, 0, 0);
            acc[0][1] = __builtin_amdgcn_mfma_f32_16x16x32_bf16(a0, bf[1][kk], acc[0][1], 0, 0, 0);
            acc[1][0] = __builtin_amdgcn_mfma_f32_16x16x32_bf16(a1, bf[0][kk], acc[1][0], 0, 0, 0);
            acc[1][1] = __builtin_amdgcn_mfma_f32_16x16x32_bf16(a1, bf[1][kk], acc[1][1], 0, 0, 0);
            acc[2][0] = __builtin_amdgcn_mfma_f32_16x16x32_bf16(a2, bf[0][kk], acc[2][0], 0, 0, 0);
            acc[2][1] = __builtin_amdgcn_mfma_f32_16x16x32_bf16(a2, bf[1][kk], acc[2][1], 0, 0, 0);
            acc[3][0] = __builtin_amdgcn_mfma_f32_16x16x32_bf16(a3, bf[0][kk], acc[3][0], 0, 0, 0);
            acc[3][1] = __builtin_amdgcn_mfma_f32_16x16x32_bf16(a3, bf[1][kk], acc[3][1], 0, 0, 0);
        }
        __builtin_amdgcn_s_setprio(0);

        // --- relu+bias -> col-major mT; C/D: row = q*4+r, col = li ---
        #pragma unroll
        for (int rt = 0; rt < 4; ++rt) {
            #pragma unroll
            for (int ct = 0; ct < 2; ++ct) {
                floatx4 a = acc[rt][ct];
                short4v s;
                float v0 = a.x + bias[ct]; s.x = f2bf(v0 > 0.f ? v0 : 0.f);
                float v1 = a.y + bias[ct]; s.y = f2bf(v1 > 0.f ? v1 : 0.f);
                float v2 = a.z + bias[ct]; s.z = f2bf(v2 > 0.f ? v2 : 0.f);
                float v3 = a.w + bias[ct]; s.w = f2bf(v3 > 0.f ? v3 : 0.f);
                *(short4v*)((short*)mT + (w * 32 + ct * 16 + li) * MT_STRIDE
                            + rt * 16 + q * 4) = s;
            }
        }
        // sync2: mT(t) visible; all waves done reading As(t).
        asm volatile("s_waitcnt lgkmcnt(0)" ::: "memory");
        __builtin_amdgcn_s_barrier();

        // --- stage tile t+EG from regs; issue gathers for t+2EG ---
        {
            int tn = t + EG;
            if (tn < NT) {
                short* ap = As + ee * A_STRIDE + 32 * ec;
                *(short8*)(ap)      = pv0;
                *(short8*)(ap + 8)  = pv1;
                *(short8*)(ap + 16) = pv2;
                *(short8*)(ap + 24) = pv3;
                *(short8*)(As + ee * A_STRIDE + IN_DIM + 8 * ec) = pe;
                if (ec == 0) dstL[nb][ee] = (short)((unsigned)rsd >> 16);

                int sd2 = psd;
                int t2 = tn + EG;
                if (t2 < NT) {
                    int t3 = t2 + EG;
                    if (t3 < NT) psd = esd[t3 * 64 + ee];
                    int s2 = sd2 & 0xFFFF;
                    const short8* nr2 = (const short8*)(nfB + (size_t)s2 * 128);
                    pv0 = nr2[4 * ec]; pv1 = nr2[4 * ec + 1];
                    pv2 = nr2[4 * ec + 2]; pv3 = nr2[4 * ec + 3];
                    pe = *(const short8*)(escT + (size_t)(t2 * 64 + ee) * 32 + ec * 8);
                    rsd = sd2;
                }
            }
        }
        __builtin_amdgcn_sched_barrier(0);  // keep prefetch issue ahead of scan

        // --- per-column run-max; dsts from LDS broadcast, SCALAR control ---
        {
            int c = tid & 127, h = tid >> 7;
            int r0 = h * 32;
            unsigned mval[32];
            #pragma unroll
            for (int j = 0; j < 4; ++j) {
                short8 v = *(const short8*)((const short*)mT + c * MT_STRIDE
                                            + r0 + 8 * j);
                #pragma unroll
                for (int k = 0; k < 8; ++k)
                    mval[8 * j + k] = (unsigned short)v[k];
            }
            const short8* dls = (const short8*)(&dstL[cb][r0]);
            int curd = 0;
            unsigned best = 0;
            #pragma unroll
            for (int j = 0; j < 4; ++j) {
                short8 dv = dls[j];
                #pragma unroll
                for (int k = 0; k < 8; ++k) {
                    int r = 8 * j + k;
                    int d = __builtin_amdgcn_readfirstlane(
                        (int)(unsigned short)dv[k]);
                    if (r == 0) {
                        curd = d; best = mval[0];
                    } else if (d != curd) {
                        atomicMax((int*)out + (size_t)curd * 128 + c,
                                  (int)(best << 16));
                        curd = d; best = mval[r];
                    } else {
                        best = best > mval[r] ? best : mval[r];
                    }
                }
            }
            atomicMax((int*)out + (size_t)curd * 128 + c, (int)(best << 16));
        }
    }
}

// ---------------------------------------------------------------------------
// Node kernel (in-place): out = (1+eps)*out + nfeat @ W_self^T + b_self
// ---------------------------------------------------------------------------
__global__ __launch_bounds__(256) void node_kernel(
    const short* __restrict__ nfB, const float* __restrict__ b_self,
    const float* __restrict__ eps, const short* __restrict__ WselfB,
    float* __restrict__ out)
{
    __shared__ short As[64 * NS];
    __shared__ short Bs[128 * NS];
    const int tid = threadIdx.x;
    const int n0 = blockIdx.x * 64;

    {
        int r = tid >> 1, h = tid & 1;
        const short8* g = (const short8*)(WselfB + r * 128 + h * 64);
        short* l = Bs + r * NS + h * 64;
        #pragma unroll
        for (int c = 0; c < 8; ++c)
            *(short8*)(l + 8 * c) = g[c];
    }
    {
        int r = tid >> 2, c = tid & 3;
        int n = n0 + r;
        short* ap = As + r * NS + 32 * c;
        if (n < NNODES) {
            const short8* nr = (const short8*)(nfB + (size_t)n * 128);
            #pragma unroll
            for (int j = 0; j < 4; ++j)
                *(short8*)(ap + 8 * j) = nr[4 * c + j];
        } else {
            #pragma unroll
            for (int j = 0; j < 4; ++j)
                *(short8*)(ap + 8 * j) = (short8){0,0,0,0,0,0,0,0};
        }
    }
    __syncthreads();

    const int lane = tid & 63;
    const int w = tid >> 6;
    const int et = w & 1;
    const int nh = w >> 1;
    const int li = lane & 15, q = lane >> 4;

    floatx4 acc[2][4];
    #pragma unroll
    for (int i = 0; i < 2; ++i)
        #pragma unroll
        for (int j = 0; j < 4; ++j)
            acc[i][j] = (floatx4){0.f, 0.f, 0.f, 0.f};

    const short* Ab = As + (et * 32 + li) * NS + q * 8;
    const short* Bb = Bs + (nh * 64 + li) * NS + q * 8;
    #pragma unroll
    for (int kk = 0; kk < 4; ++kk) {
        short8 a0 = *(const short8*)(Ab + kk * 32);
        short8 a1 = *(const short8*)(Ab + 16 * NS + kk * 32);
        short8 b0 = *(const short8*)(Bb + kk * 32);
        short8 b1 = *(const short8*)(Bb + 16 * NS + kk * 32);
        short8 b2 = *(const short8*)(Bb + 32 * NS + kk * 32);
        short8 b3 = *(const short8*)(Bb + 48 * NS + kk * 32);
        MFMA8(acc, a0, a1, b0, b1, b2, b3)
    }

    const float epsv = 1.0f + eps[0];
    #pragma unroll
    for (int ta = 0; ta < 2; ++ta) {
        #pragma unroll
        for (int r = 0; r < 4; ++r) {
            int n = n0 + et * 32 + ta * 16 + q * 4 + r;
            if (n < NNODES) {
                #pragma unroll
                for (int tb = 0; tb < 4; ++tb) {
                    int o = nh * 64 + tb * 16 + li;
                    float v = acc[ta][tb][r] + b_self[o]
                            + epsv * out[(size_t)n * 128 + o];
                    out[(size_t)n * 128 + o] = v;
                }
            }
        }
    }
}

// ===========================================================================
// Fallback kernels (direct path) — used only if ws_size too small.
// ===========================================================================
__global__ void prep_w(const float* __restrict__ W_edge,
                       const float* __restrict__ W_ne,
                       const float* __restrict__ W_self,
                       short* __restrict__ WcatB, short* __restrict__ WselfB)
{
    int idx = blockIdx.x * 256 + threadIdx.x;
    if (idx < OUT_DIM * KDIM) {
        int n = idx / KDIM, k = idx - n * KDIM;
        float val;
        if (k < IN_DIM) {
            val = W_ne[n * 256 + k];
        } else {
            int j = k - IN_DIM;
            float s = 0.f;
            for (int kk = 0; kk < 128; ++kk)
                s += W_ne[n * 256 + 128 + kk] * W_edge[kk * 32 + j];
            val = s;
        }
        WcatB[idx] = f2bf(val);
    } else if (idx < OUT_DIM * KDIM + OUT_DIM * IN_DIM) {
        int s = idx - OUT_DIM * KDIM;
        WselfB[s] = f2bf(W_self[s]);
    }
}

__global__ __launch_bounds__(256) void edge_direct(
    const float* __restrict__ nfeat, const float* __restrict__ etype,
    const int* __restrict__ src, const int* __restrict__ dst,
    const float* __restrict__ b_ne, const short* __restrict__ WcatB,
    float* __restrict__ out)
{
    __shared__ short As[64 * A_STRIDE];
    __shared__ short Bs[128 * A_STRIDE];
    const int tid = threadIdx.x;
    const int e0 = blockIdx.x * 64;
    {
        int r = tid >> 1, h = tid & 1;
        const short8* g = (const short8*)(WcatB + r * KDIM + h * 80);
        short* l = Bs + r * A_STRIDE + h * 80;
        #pragma unroll
        for (int c = 0; c < 10; ++c) *(short8*)(l + 8 * c) = g[c];
    }
    {
        const floatx4* ge = (const floatx4*)(etype + (size_t)e0 * 32);
        #pragma unroll
        for (int i = 0; i < 2; ++i) {
            int f = tid + i * 256;
            int e = f >> 3, c = f & 7;
            store_bf4(As + e * A_STRIDE + IN_DIM + 4 * c, ge[f]);
        }
    }
    {
        int g = tid & 15, eo = tid >> 4;
        #pragma unroll
        for (int p = 0; p < 4; ++p) {
            int e = eo + p * 16;
            int s = src[e0 + e];
            const floatx4* row = (const floatx4*)(nfeat + (size_t)s * 128);
            floatx4 v0 = row[g];
            floatx4 v1 = row[g + 16];
            store_bf4(As + e * A_STRIDE + 4 * g, v0);
            store_bf4(As + e * A_STRIDE + 64 + 4 * g, v1);
        }
    }
    __syncthreads();
    const int lane = tid & 63;
    const int w = tid >> 6;
    const int et = w & 1, nh = w >> 1;
    const int li = lane & 15, q = lane >> 4;
    floatx4 acc[2][4];
    #pragma unroll
    for (int i = 0; i < 2; ++i)
        #pragma unroll
        for (int j = 0; j < 4; ++j)
            acc[i][j] = (floatx4){0.f, 0.f, 0.f, 0.f};
    const short* Ab = As + (et * 32 + li) * A_STRIDE + q * 8;
    const short* Bb = Bs + (nh * 64 + li) * A_STRIDE + q * 8;
    #pragma unroll
    for (int kk = 0; kk < 5; ++kk) {
        short8 a0 = *(const short8*)(Ab + kk * 32);
        short8 a1 = *(const short8*)(Ab + 16 * A_STRIDE + kk * 32);
        short8 b0 = *(const short8*)(Bb + kk * 32);
        short8 b1 = *(const short8*)(Bb + 16 * A_STRIDE + kk * 32);
        short8 b2 = *(const short8*)(Bb + 32 * A_STRIDE + kk * 32);
        short8 b3 = *(const short8*)(Bb + 48 * A_STRIDE + kk * 32);
        MFMA8(acc, a0, a1, b0, b1, b2, b3)
    }
    #pragma unroll
    for (int ta = 0; ta < 2; ++ta) {
        #pragma unroll
        for (int r = 0; r < 4; ++r) {
            int el = et * 32 + ta * 16 + q * 4 + r;
            int d = dst[e0 + el];
            int* nrow = (int*)out + (size_t)d * 128;
            #pragma unroll
            for (int tb = 0; tb < 4; ++tb) {
                int o = nh * 64 + tb * 16 + li;
                float v = acc[ta][tb][r] + b_ne[o];
                v = v > 0.f ? v : 0.f;
                atomicMax(nrow + o, __float_as_int(v));
            }
        }
    }
}

__global__ __launch_bounds__(256) void node_direct(
    const float* __restrict__ nfeat, const float* __restrict__ b_self,
    const float* __restrict__ eps, const short* __restrict__ WselfB,
    float* __restrict__ out)
{
    __shared__ short As[64 * NS];
    __shared__ short Bs[128 * NS];
    const int tid = threadIdx.x;
    const int n0 = blockIdx.x * 64;
    {
        int r = tid >> 1, h = tid & 1;
        const short8* g = (const short8*)(WselfB + r * 128 + h * 64);
        short* l = Bs + r * NS + h * 64;
        #pragma unroll
        for (int c = 0; c < 8; ++c) *(short8*)(l + 8 * c) = g[c];
    }
    {
        int r = tid >> 2, fi = tid & 3;
        int n = n0 + r;
        if (n < NNODES) {
            const floatx4* row = (const floatx4*)(nfeat + (size_t)n * 128);
            #pragma unroll
            for (int p = 0; p < 8; ++p) {
                int f = fi + 4 * p;
                store_bf4(As + r * NS + 4 * f, row[f]);
            }
        } else {
            #pragma unroll
            for (int p = 0; p < 8; ++p) {
                int f = fi + 4 * p;
                *(short4v*)(As + r * NS + 4 * f) = (short4v){0, 0, 0, 0};
            }
        }
    }
    __syncthreads();
    const int lane = tid & 63;
    const int w = tid >> 6;
    const int et = w & 1, nh = w >> 1;
    const int li = lane & 15, q = lane >> 4;
    floatx4 acc[2][4];
    #pragma unroll
    for (int i = 0; i < 2; ++i)
        #pragma unroll
        for (int j = 0; j < 4; ++j)
            acc[i][j] = (floatx4){0.f, 0.f, 0.f, 0.f};
    const short* Ab = As + (et * 32 + li) * NS + q * 8;
    const short* Bb = Bs + (nh * 64 + li) * NS + q * 8;
    #pragma unroll
    for (int kk = 0; kk < 4; ++kk) {
        short8 a0 = *(const short8*)(Ab + kk * 32);
        short8 a1 = *(const short8*)(Ab + 16 * NS + kk * 32);
        short8 b0 = *(const short8*)(Bb + kk * 32);
        short8 b1 = *(const short8*)(Bb + 16 * NS + kk * 32);
        short8 b2 = *(const short8*)(Bb + 32 * NS + kk * 32);
        short8 b3 = *(const short8*)(Bb + 48 * NS + kk * 32);
        MFMA8(acc, a0, a1, b0, b1, b2, b3)
    }
    const float epsv = 1.0f + eps[0];
    #pragma unroll
    for (int ta = 0; ta < 2; ++ta) {
        #pragma unroll
        for (int r = 0; r < 4; ++r) {
            int n = n0 + et * 32 + ta * 16 + q * 4 + r;
            if (n < NNODES) {
                #pragma unroll
                for (int tb = 0; tb < 4; ++tb) {
                    int o = nh * 64 + tb * 16 + li;
                    float v = acc[ta][tb][r] + b_self[o]
                            + epsv * out[(size_t)n * 128 + o];
                    out[(size_t)n * 128 + o] = v;
                }
            }
        }
    }
}

// ---------------------------------------------------------------------------
extern "C" void kernel_launch(void* const* d_in, const int* in_sizes, int n_in,
                              void* d_out, int out_size, void* d_ws, size_t ws_size,
                              hipStream_t stream) {
    const float* nfeat  = (const float*)d_in[0];
    const float* etype  = (const float*)d_in[1];
    const int*   src    = (const int*)d_in[2];
    const int*   dst    = (const int*)d_in[3];
    const float* W_edge = (const float*)d_in[4];
    const float* W_ne   = (const float*)d_in[5];
    const float* b_ne   = (const float*)d_in[6];
    const float* W_self = (const float*)d_in[7];
    const float* b_self = (const float*)d_in[8];
    const float* eps    = (const float*)d_in[9];
    float* out = (float*)d_out;

    char* ws = (char*)d_ws;
    size_t off = 0;
    auto alloc = [&](size_t bytes) { void* p = ws + off; off = (off + bytes + 255) & ~(size_t)255; return p; };
    int*   cnt    = (int*)alloc((size_t)NNODES * 4);
    int*   cur    = (int*)alloc((size_t)NNODES * 4);
    int*   esd    = (int*)alloc((size_t)NEDGES * 4);
    short* escT   = (short*)alloc((size_t)NEDGES * EDGE_DIM * 2);
    short* nfB    = (short*)alloc((size_t)NNODES * IN_DIM * 2);
    short* WcatB  = (short*)alloc((size_t)OUT_DIM * KDIM * 2);
    short* WselfB = (short*)alloc((size_t)OUT_DIM * IN_DIM * 2);
    int*   bsum   = (int*)alloc((size_t)NSCB * 4);
    int*   boff   = (int*)alloc((size_t)NSCB * 4);
    size_t need = off;

    if (ws_size >= need) {
        hipMemsetAsync(cnt, 0, (size_t)NNODES * 4, stream);
        hipMemsetAsync(out, 0, (size_t)NNODES * OUT_DIM * sizeof(float), stream);
        prep_kernel<<<1024, 256, 0, stream>>>(nfeat, dst, W_edge, W_ne, W_self,
                                              cnt, nfB, WcatB, WselfB);
        scan_part<<<NSCB, 256, 0, stream>>>(cnt, bsum);
        scan_mid<<<1, 64, 0, stream>>>(bsum, boff);
        scan_write<<<NSCB, 256, 0, stream>>>(cnt, boff, cur);
        scatter_kernel<<<2048, 256, 0, stream>>>(src, dst, etype, cur, esd, escT);
        edge_kernel<<<EG, 256, 0, stream>>>(nfB, escT, esd, b_ne, WcatB, out);
        node_kernel<<<(NNODES + 63) / 64, 256, 0, stream>>>(nfB, b_self, eps,
                                                            WselfB, out);
    } else {
        short* WcatB2  = (short*)d_ws;
        short* WselfB2 = WcatB2 + (size_t)OUT_DIM * KDIM;
        hipMemsetAsync(out, 0, (size_t)NNODES * 128 * sizeof(float), stream);
        prep_w<<<144, 256, 0, stream>>>(W_edge, W_ne, W_self, WcatB2, WselfB2);
        edge_direct<<<NEDGES / 64, 256, 0, stream>>>(nfeat, etype, src, dst,
                                                     b_ne, WcatB2, out);
        node_direct<<<(NNODES + 63) / 64, 256, 0, stream>>>(nfeat, b_self, eps,
                                                            WselfB2, out);
    }
}

// Round 8
// 345.886 us; speedup vs baseline: 1.2401x; 1.0168x over previous
//
#include <hip/hip_runtime.h>
#include <hip/hip_bf16.h>

#define NNODES 50000
#define NEDGES 800000
#define IN_DIM 128
#define EDGE_DIM 32
#define OUT_DIM 128
#define KDIM 160          // IN_DIM + EDGE_DIM
#define A_STRIDE 168      // 160 + 8 pad, 16B aligned rows
#define NS 136            // 128 + 8 pad for node kernel
#define MT_STRIDE 72      // col-major m-tile: 72 shorts = 144 B (16B-aligned rows)
#define NT (NEDGES / 64)  // 12500 edge tiles
#define EG 1024           // edge grid: 4 blocks/CU, strided tile assignment
#define NSCB 49           // scan blocks: 49*1024 >= 50000

typedef __attribute__((ext_vector_type(8))) short short8;
typedef __attribute__((ext_vector_type(4))) short short4v;
typedef __attribute__((ext_vector_type(4))) float floatx4;

__device__ __forceinline__ short f2bf(float f) {
    union { float f; unsigned u; } v; v.f = f;
    unsigned r = (v.u + 0x7FFFu + ((v.u >> 16) & 1u)) >> 16;  // RNE
    return (short)r;
}

__device__ __forceinline__ void store_bf4(short* p, floatx4 v) {
    short4v s;
    s.x = f2bf(v.x); s.y = f2bf(v.y); s.z = f2bf(v.z); s.w = f2bf(v.w);
    *(short4v*)p = s;
}

__device__ __forceinline__ void store_bf8(short* p, floatx4 a, floatx4 b) {
    short8 s;
    s[0] = f2bf(a.x); s[1] = f2bf(a.y); s[2] = f2bf(a.z); s[3] = f2bf(a.w);
    s[4] = f2bf(b.x); s[5] = f2bf(b.y); s[6] = f2bf(b.z); s[7] = f2bf(b.w);
    *(short8*)p = s;
}

#define MFMA8(ACC, A0, A1, B0, B1, B2, B3)                                        \
    ACC[0][0] = __builtin_amdgcn_mfma_f32_16x16x32_bf16(A0, B0, ACC[0][0], 0, 0, 0); \
    ACC[0][1] = __builtin_amdgcn_mfma_f32_16x16x32_bf16(A0, B1, ACC[0][1], 0, 0, 0); \
    ACC[0][2] = __builtin_amdgcn_mfma_f32_16x16x32_bf16(A0, B2, ACC[0][2], 0, 0, 0); \
    ACC[0][3] = __builtin_amdgcn_mfma_f32_16x16x32_bf16(A0, B3, ACC[0][3], 0, 0, 0); \
    ACC[1][0] = __builtin_amdgcn_mfma_f32_16x16x32_bf16(A1, B0, ACC[1][0], 0, 0, 0); \
    ACC[1][1] = __builtin_amdgcn_mfma_f32_16x16x32_bf16(A1, B1, ACC[1][1], 0, 0, 0); \
    ACC[1][2] = __builtin_amdgcn_mfma_f32_16x16x32_bf16(A1, B2, ACC[1][2], 0, 0, 0); \
    ACC[1][3] = __builtin_amdgcn_mfma_f32_16x16x32_bf16(A1, B3, ACC[1][3], 0, 0, 0);

// ---------------------------------------------------------------------------
// Prep: nfeat -> bf16 table, folded weights, AND dst histogram.
// (cnt and out pre-zeroed by hipMemsetAsync before this kernel.)
// ---------------------------------------------------------------------------
__global__ __launch_bounds__(256) void prep_kernel(
    const float* __restrict__ nfeat, const int* __restrict__ dst,
    const float* __restrict__ W_edge, const float* __restrict__ W_ne,
    const float* __restrict__ W_self,
    int* __restrict__ cnt, short* __restrict__ nfB,
    short* __restrict__ WcatB, short* __restrict__ WselfB)
{
    int gid = blockIdx.x * 256 + threadIdx.x;
    int GS = gridDim.x * 256;
    for (int i = gid; i < NNODES * IN_DIM / 8; i += GS) {
        floatx4 a = ((const floatx4*)nfeat)[2 * i];
        floatx4 b = ((const floatx4*)nfeat)[2 * i + 1];
        store_bf8(nfB + 8 * i, a, b);
    }
    for (int idx = gid; idx < OUT_DIM * KDIM + OUT_DIM * IN_DIM; idx += GS) {
        if (idx < OUT_DIM * KDIM) {
            int n = idx / KDIM, k = idx - n * KDIM;
            float val;
            if (k < IN_DIM) {
                val = W_ne[n * 256 + k];
            } else {
                int j = k - IN_DIM;
                float s = 0.f;
                for (int kk = 0; kk < 128; ++kk)
                    s += W_ne[n * 256 + 128 + kk] * W_edge[kk * 32 + j];
                val = s;
            }
            WcatB[idx] = f2bf(val);
        } else {
            int s = idx - OUT_DIM * KDIM;
            WselfB[s] = f2bf(W_self[s]);
        }
    }
    for (int e = gid; e < NEDGES; e += GS)
        atomicAdd(&cnt[dst[e]], 1);
}

// ---------------------------------------------------------------------------
// Parallel counting-sort scan:
//   scan_part : 49 blocks x 256 thr, int4/thread -> block sums
//   scan_mid  : 1 block x 64 thr, exclusive scan of 49 block sums
//   scan_write: 49 blocks x 256 thr, in-block exclusive scan + boff -> cur
// ---------------------------------------------------------------------------
__global__ __launch_bounds__(256) void scan_part(const int* __restrict__ cnt,
                                                 int* __restrict__ bsum) {
    __shared__ int red[256];
    int b = blockIdx.x, t = threadIdx.x;
    int idx = b * 1024 + t * 4;
    int4 v = {0, 0, 0, 0};
    if (idx < NNODES) v = *(const int4*)(cnt + idx);   // NNODES % 4 == 0
    red[t] = v.x + v.y + v.z + v.w;
    __syncthreads();
    for (int off = 128; off > 0; off >>= 1) {
        if (t < off) red[t] += red[t + off];
        __syncthreads();
    }
    if (t == 0) bsum[b] = red[0];
}

__global__ __launch_bounds__(64) void scan_mid(const int* __restrict__ bsum,
                                               int* __restrict__ boff) {
    __shared__ int a[64], b[64];
    int t = threadIdx.x;
    int v = (t < NSCB) ? bsum[t] : 0;
    a[t] = v;
    __syncthreads();
    int* in = a; int* out = b;
    for (int off = 1; off < 64; off <<= 1) {
        out[t] = in[t] + (t >= off ? in[t - off] : 0);
        __syncthreads();
        int* tmp = in; in = out; out = tmp;
    }
    if (t < NSCB) boff[t] = in[t] - v;     // exclusive
}

__global__ __launch_bounds__(256) void scan_write(const int* __restrict__ cnt,
                                                  const int* __restrict__ boff,
                                                  int* __restrict__ cur) {
    __shared__ int a[256], bb[256];
    int b = blockIdx.x, t = threadIdx.x;
    int idx = b * 1024 + t * 4;
    int4 v = {0, 0, 0, 0};
    if (idx < NNODES) v = *(const int4*)(cnt + idx);
    int s = v.x + v.y + v.z + v.w;
    a[t] = s;
    __syncthreads();
    int* in = a; int* out = bb;
    for (int off = 1; off < 256; off <<= 1) {
        out[t] = in[t] + (t >= off ? in[t - off] : 0);
        __syncthreads();
        int* tmp = in; in = out; out = tmp;
    }
    if (idx < NNODES) {
        int base = boff[b] + in[t] - s;    // exclusive prefix for this thread
        cur[idx] = base;     base += v.x;
        cur[idx + 1] = base; base += v.y;
        cur[idx + 2] = base; base += v.z;
        cur[idx + 3] = base;
    }
}

// ---------------------------------------------------------------------------
// Scatter, 8-lanes-per-edge cooperative: a wave handles 8 consecutive edges.
// Group leaders (lane%8==0) do the atomicAdd in ONE exec-masked instruction;
// __shfl broadcasts pos within each group. Each lane reads one floatx4 of
// the etype row (wave reads 8 rows = 1 KB fully coalesced per load instr);
// each group stores 64 B contiguous bf16.
// ---------------------------------------------------------------------------
__global__ __launch_bounds__(256) void scatter_kernel(
    const int* __restrict__ src, const int* __restrict__ dst,
    const float* __restrict__ etype,
    int* __restrict__ cur,      // cursor (destroyed)
    int* __restrict__ esd, short* __restrict__ escT) {
    const int tid = threadIdx.x;
    const int lane = tid & 63;
    const int g = lane & 7;                       // lane within 8-lane group
    const int ldr = lane & ~7;                    // group-leader lane id
    const int grp = tid >> 3;                     // group id within block (0..31)
    const int GS = gridDim.x * 32;
    for (int e = blockIdx.x * 32 + grp; e < NEDGES; e += GS) {
        int pos = 0;
        if (g == 0) {
            int d = dst[e];
            int s = src[e];
            pos = atomicAdd(&cur[d], 1);
            esd[pos] = (int)((unsigned)s | ((unsigned)d << 16));
        }
        pos = __shfl(pos, ldr);                   // broadcast within group
        floatx4 v = ((const floatx4*)(etype + (size_t)e * 32))[g];
        store_bf4(escT + (size_t)pos * 32 + g * 4, v);
    }
}

// ---------------------------------------------------------------------------
// Edge kernel: persistent, strided tiles, now 4 blocks/CU (16 waves/CU).
// R2's 4-block attempt failed from VGPR-squeeze spills (live set then ~128;
// WRITE 37->86 MB). Current slim kernel is VGPR=72 << 128 cap, LDS
// 40448*4 = 161792 <= 163840 -> 4 blocks fit WITHOUT spills. Latency-bound
// kernel (no pipe >33%) -> +33% waves should convert directly.
// WRITE_SIZE is the spill tripwire: must stay ~36.7 MB.
// ---------------------------------------------------------------------------
__global__ __launch_bounds__(256, 4) void edge_kernel(
    const short* __restrict__ nfB, const short* __restrict__ escT,
    const int* __restrict__ esd, const float* __restrict__ b_ne,
    const short* __restrict__ WcatB, float* __restrict__ out)
{
    __shared__ short As[64 * A_STRIDE];            // 21504 B
    __shared__ unsigned short mT[128 * MT_STRIDE]; // 18432 B, col-major [o][el]
    __shared__ short dstL[2][64];                  // 256 B, double-buffered dsts

    const int tid = threadIdx.x;
    const int lane = tid & 63;
    const int w = tid >> 6;                        // wave id: cols w*32..w*32+31
    const int li = lane & 15, q = lane >> 4;

    // --- B-fragments to registers (once per block; L2-hot) ---
    short8 bf[2][5];
    #pragma unroll
    for (int ct = 0; ct < 2; ++ct)
        #pragma unroll
        for (int kk = 0; kk < 5; ++kk)
            bf[ct][kk] = *(const short8*)(WcatB +
                (size_t)(w * 32 + ct * 16 + li) * KDIM + kk * 32 + q * 8);

    float bias[2];
    #pragma unroll
    for (int ct = 0; ct < 2; ++ct) bias[ct] = b_ne[w * 32 + ct * 16 + li];

    const int ee = tid >> 2, ec = tid & 3;         // 4 threads per edge row

    short8 pv0, pv1, pv2, pv3;                     // prefetched nfB row quarter
    short8 pe;                                     // prefetched escT quarter
    int rsd = 0;                                   // record matching pv*/pe
    int psd = 0;                                   // record for t+2EG

    const int tA = blockIdx.x;                     // first tile (strided by EG)

    // --- prologue: stage tile tA; load heavy(tA+EG); psd = rec(tA+2EG) ---
    {
        int sd = esd[tA * 64 + ee];
        int s = sd & 0xFFFF;
        const short8* nr = (const short8*)(nfB + (size_t)s * 128);
        pv0 = nr[4 * ec]; pv1 = nr[4 * ec + 1];
        pv2 = nr[4 * ec + 2]; pv3 = nr[4 * ec + 3];
        pe = *(const short8*)(escT + (size_t)(tA * 64 + ee) * 32 + ec * 8);

        int tB = tA + EG;
        int sdB = 0;
        if (tB < NT) sdB = esd[tB * 64 + ee];

        short* ap = As + ee * A_STRIDE + 32 * ec;
        *(short8*)(ap)      = pv0;
        *(short8*)(ap + 8)  = pv1;
        *(short8*)(ap + 16) = pv2;
        *(short8*)(ap + 24) = pv3;
        *(short8*)(As + ee * A_STRIDE + IN_DIM + 8 * ec) = pe;
        if (ec == 0) dstL[0][ee] = (short)((unsigned)sd >> 16);

        if (tB < NT) {
            int sB = sdB & 0xFFFF;
            const short8* nrB = (const short8*)(nfB + (size_t)sB * 128);
            pv0 = nrB[4 * ec]; pv1 = nrB[4 * ec + 1];
            pv2 = nrB[4 * ec + 2]; pv3 = nrB[4 * ec + 3];
            pe = *(const short8*)(escT + (size_t)(tB * 64 + ee) * 32 + ec * 8);
            rsd = sdB;
            int tC = tB + EG;
            if (tC < NT) psd = esd[tC * 64 + ee];
        }
    }

    int it = 0;
    for (int t = tA; t < NT; t += EG, ++it) {
        const int cb = it & 1, nb = cb ^ 1;

        // sync1: As(t)/dstL(t) visible. lgkm-only: prefetch stays in flight.
        asm volatile("s_waitcnt lgkmcnt(0)" ::: "memory");
        __builtin_amdgcn_s_barrier();

        floatx4 acc[4][2];                         // [row-tile][col-tile]
        #pragma unroll
        for (int i = 0; i < 4; ++i)
            #pragma unroll
            for (int j = 0; j < 2; ++j)
                acc[i][j] = (floatx4){0.f, 0.f, 0.f, 0.f};

        __builtin_amdgcn_s_setprio(1);
        #pragma unroll
        for (int kk = 0; kk < 5; ++kk) {
            short8 a0 = *(const short8*)(As + (0 * 16 + li) * A_STRIDE + kk * 32 + q * 8);
            short8 a1 = *(const short8*)(As + (1 * 16 + li) * A_STRIDE + kk * 32 + q * 8);
            short8 a2 = *(const short8*)(As + (2 * 16 + li) * A_STRIDE + kk * 32 + q * 8);
            short8 a3 = *(const short8*)(As + (3 * 16 + li) * A_STRIDE + kk * 32 + q * 8);
            acc[0][0] = __builtin_amdgcn_mfma_f32_16x16x32_bf16(a0, bf[0][kk], acc[0][0], 0, 0, 0);
            acc[0][1] = __builtin_amdgcn_mfma_f32_16x16x32_bf16(a0, bf[1][kk], acc[0][1], 0, 0, 0);
            acc[1][0] = __builtin_amdgcn_mfma_f32_16x16x32_bf16(a1, bf[0][kk], acc[1][0], 0, 0, 0);
            acc[1][1] = __builtin_amdgcn_mfma_f32_16x16x32_bf16(a1, bf[1][kk], acc[1][1], 0, 0, 0);
            acc[2][0] = __builtin_amdgcn_mfma_f32_16x16x32_bf16(a2, bf[0][kk], acc[2][0], 0, 0, 0);
            acc[2][1] = __builtin_amdgcn_mfma_f32_16x16x32_bf16(a2, bf[1][kk], acc[2][1], 0, 0, 0);
            acc[3][0] = __builtin_amdgcn_mfma_f32_16x16x32_bf16(a3, bf[0][kk], acc[3][0], 0, 0, 0);
            acc[3][1] = __builtin_amdgcn_mfma_f32_16x16x32_bf16(a3, bf[1][kk], acc[3][1], 0, 0, 0);
        }
        __builtin_amdgcn_s_setprio(0);

        // --- relu+bias -> col-major mT; C/D: row = q*4+r, col = li ---
        #pragma unroll
        for (int rt = 0; rt < 4; ++rt) {
            #pragma unroll
            for (int ct = 0; ct < 2; ++ct) {
                floatx4 a = acc[rt][ct];
                short4v s;
                float v0 = a.x + bias[ct]; s.x = f2bf(v0 > 0.f ? v0 : 0.f);
                float v1 = a.y + bias[ct]; s.y = f2bf(v1 > 0.f ? v1 : 0.f);
                float v2 = a.z + bias[ct]; s.z = f2bf(v2 > 0.f ? v2 : 0.f);
                float v3 = a.w + bias[ct]; s.w = f2bf(v3 > 0.f ? v3 : 0.f);
                *(short4v*)((short*)mT + (w * 32 + ct * 16 + li) * MT_STRIDE
                            + rt * 16 + q * 4) = s;
            }
        }
        // sync2: mT(t) visible; all waves done reading As(t).
        asm volatile("s_waitcnt lgkmcnt(0)" ::: "memory");
        __builtin_amdgcn_s_barrier();

        // --- stage tile t+EG from regs; issue gathers for t+2EG ---
        {
            int tn = t + EG;
            if (tn < NT) {
                short* ap = As + ee * A_STRIDE + 32 * ec;
                *(short8*)(ap)      = pv0;
                *(short8*)(ap + 8)  = pv1;
                *(short8*)(ap + 16) = pv2;
                *(short8*)(ap + 24) = pv3;
                *(short8*)(As + ee * A_STRIDE + IN_DIM + 8 * ec) = pe;
                if (ec == 0) dstL[nb][ee] = (short)((unsigned)rsd >> 16);

                int sd2 = psd;
                int t2 = tn + EG;
                if (t2 < NT) {
                    int t3 = t2 + EG;
                    if (t3 < NT) psd = esd[t3 * 64 + ee];
                    int s2 = sd2 & 0xFFFF;
                    const short8* nr2 = (const short8*)(nfB + (size_t)s2 * 128);
                    pv0 = nr2[4 * ec]; pv1 = nr2[4 * ec + 1];
                    pv2 = nr2[4 * ec + 2]; pv3 = nr2[4 * ec + 3];
                    pe = *(const short8*)(escT + (size_t)(t2 * 64 + ee) * 32 + ec * 8);
                    rsd = sd2;
                }
            }
        }
        __builtin_amdgcn_sched_barrier(0);  // keep prefetch issue ahead of scan

        // --- per-column run-max; dsts from LDS broadcast, SCALAR control ---
        {
            int c = tid & 127, h = tid >> 7;
            int r0 = h * 32;
            unsigned mval[32];
            #pragma unroll
            for (int j = 0; j < 4; ++j) {
                short8 v = *(const short8*)((const short*)mT + c * MT_STRIDE
                                            + r0 + 8 * j);
                #pragma unroll
                for (int k = 0; k < 8; ++k)
                    mval[8 * j + k] = (unsigned short)v[k];
            }
            const short8* dls = (const short8*)(&dstL[cb][r0]);
            int curd = 0;
            unsigned best = 0;
            #pragma unroll
            for (int j = 0; j < 4; ++j) {
                short8 dv = dls[j];
                #pragma unroll
                for (int k = 0; k < 8; ++k) {
                    int r = 8 * j + k;
                    int d = __builtin_amdgcn_readfirstlane(
                        (int)(unsigned short)dv[k]);
                    if (r == 0) {
                        curd = d; best = mval[0];
                    } else if (d != curd) {
                        atomicMax((int*)out + (size_t)curd * 128 + c,
                                  (int)(best << 16));
                        curd = d; best = mval[r];
                    } else {
                        best = best > mval[r] ? best : mval[r];
                    }
                }
            }
            atomicMax((int*)out + (size_t)curd * 128 + c, (int)(best << 16));
        }
    }
}

// ---------------------------------------------------------------------------
// Node kernel (in-place): out = (1+eps)*out + nfeat @ W_self^T + b_self
// ---------------------------------------------------------------------------
__global__ __launch_bounds__(256) void node_kernel(
    const short* __restrict__ nfB, const float* __restrict__ b_self,
    const float* __restrict__ eps, const short* __restrict__ WselfB,
    float* __restrict__ out)
{
    __shared__ short As[64 * NS];
    __shared__ short Bs[128 * NS];
    const int tid = threadIdx.x;
    const int n0 = blockIdx.x * 64;

    {
        int r = tid >> 1, h = tid & 1;
        const short8* g = (const short8*)(WselfB + r * 128 + h * 64);
        short* l = Bs + r * NS + h * 64;
        #pragma unroll
        for (int c = 0; c < 8; ++c)
            *(short8*)(l + 8 * c) = g[c];
    }
    {
        int r = tid >> 2, c = tid & 3;
        int n = n0 + r;
        short* ap = As + r * NS + 32 * c;
        if (n < NNODES) {
            const short8* nr = (const short8*)(nfB + (size_t)n * 128);
            #pragma unroll
            for (int j = 0; j < 4; ++j)
                *(short8*)(ap + 8 * j) = nr[4 * c + j];
        } else {
            #pragma unroll
            for (int j = 0; j < 4; ++j)
                *(short8*)(ap + 8 * j) = (short8){0,0,0,0,0,0,0,0};
        }
    }
    __syncthreads();

    const int lane = tid & 63;
    const int w = tid >> 6;
    const int et = w & 1;
    const int nh = w >> 1;
    const int li = lane & 15, q = lane >> 4;

    floatx4 acc[2][4];
    #pragma unroll
    for (int i = 0; i < 2; ++i)
        #pragma unroll
        for (int j = 0; j < 4; ++j)
            acc[i][j] = (floatx4){0.f, 0.f, 0.f, 0.f};

    const short* Ab = As + (et * 32 + li) * NS + q * 8;
    const short* Bb = Bs + (nh * 64 + li) * NS + q * 8;
    #pragma unroll
    for (int kk = 0; kk < 4; ++kk) {
        short8 a0 = *(const short8*)(Ab + kk * 32);
        short8 a1 = *(const short8*)(Ab + 16 * NS + kk * 32);
        short8 b0 = *(const short8*)(Bb + kk * 32);
        short8 b1 = *(const short8*)(Bb + 16 * NS + kk * 32);
        short8 b2 = *(const short8*)(Bb + 32 * NS + kk * 32);
        short8 b3 = *(const short8*)(Bb + 48 * NS + kk * 32);
        MFMA8(acc, a0, a1, b0, b1, b2, b3)
    }

    const float epsv = 1.0f + eps[0];
    #pragma unroll
    for (int ta = 0; ta < 2; ++ta) {
        #pragma unroll
        for (int r = 0; r < 4; ++r) {
            int n = n0 + et * 32 + ta * 16 + q * 4 + r;
            if (n < NNODES) {
                #pragma unroll
                for (int tb = 0; tb < 4; ++tb) {
                    int o = nh * 64 + tb * 16 + li;
                    float v = acc[ta][tb][r] + b_self[o]
                            + epsv * out[(size_t)n * 128 + o];
                    out[(size_t)n * 128 + o] = v;
                }
            }
        }
    }
}

// ===========================================================================
// Fallback kernels (direct path) — used only if ws_size too small.
// ===========================================================================
__global__ void prep_w(const float* __restrict__ W_edge,
                       const float* __restrict__ W_ne,
                       const float* __restrict__ W_self,
                       short* __restrict__ WcatB, short* __restrict__ WselfB)
{
    int idx = blockIdx.x * 256 + threadIdx.x;
    if (idx < OUT_DIM * KDIM) {
        int n = idx / KDIM, k = idx - n * KDIM;
        float val;
        if (k < IN_DIM) {
            val = W_ne[n * 256 + k];
        } else {
            int j = k - IN_DIM;
            float s = 0.f;
            for (int kk = 0; kk < 128; ++kk)
                s += W_ne[n * 256 + 128 + kk] * W_edge[kk * 32 + j];
            val = s;
        }
        WcatB[idx] = f2bf(val);
    } else if (idx < OUT_DIM * KDIM + OUT_DIM * IN_DIM) {
        int s = idx - OUT_DIM * KDIM;
        WselfB[s] = f2bf(W_self[s]);
    }
}

__global__ __launch_bounds__(256) void edge_direct(
    const float* __restrict__ nfeat, const float* __restrict__ etype,
    const int* __restrict__ src, const int* __restrict__ dst,
    const float* __restrict__ b_ne, const short* __restrict__ WcatB,
    float* __restrict__ out)
{
    __shared__ short As[64 * A_STRIDE];
    __shared__ short Bs[128 * A_STRIDE];
    const int tid = threadIdx.x;
    const int e0 = blockIdx.x * 64;
    {
        int r = tid >> 1, h = tid & 1;
        const short8* g = (const short8*)(WcatB + r * KDIM + h * 80);
        short* l = Bs + r * A_STRIDE + h * 80;
        #pragma unroll
        for (int c = 0; c < 10; ++c) *(short8*)(l + 8 * c) = g[c];
    }
    {
        const floatx4* ge = (const floatx4*)(etype + (size_t)e0 * 32);
        #pragma unroll
        for (int i = 0; i < 2; ++i) {
            int f = tid + i * 256;
            int e = f >> 3, c = f & 7;
            store_bf4(As + e * A_STRIDE + IN_DIM + 4 * c, ge[f]);
        }
    }
    {
        int g = tid & 15, eo = tid >> 4;
        #pragma unroll
        for (int p = 0; p < 4; ++p) {
            int e = eo + p * 16;
            int s = src[e0 + e];
            const floatx4* row = (const floatx4*)(nfeat + (size_t)s * 128);
            floatx4 v0 = row[g];
            floatx4 v1 = row[g + 16];
            store_bf4(As + e * A_STRIDE + 4 * g, v0);
            store_bf4(As + e * A_STRIDE + 64 + 4 * g, v1);
        }
    }
    __syncthreads();
    const int lane = tid & 63;
    const int w = tid >> 6;
    const int et = w & 1, nh = w >> 1;
    const int li = lane & 15, q = lane >> 4;
    floatx4 acc[2][4];
    #pragma unroll
    for (int i = 0; i < 2; ++i)
        #pragma unroll
        for (int j = 0; j < 4; ++j)
            acc[i][j] = (floatx4){0.f, 0.f, 0.f, 0.f};
    const short* Ab = As + (et * 32 + li) * A_STRIDE + q * 8;
    const short* Bb = Bs + (nh * 64 + li) * A_STRIDE + q * 8;
    #pragma unroll
    for (int kk = 0; kk < 5; ++kk) {
        short8 a0 = *(const short8*)(Ab + kk * 32);
        short8 a1 = *(const short8*)(Ab + 16 * A_STRIDE + kk * 32);
        short8 b0 = *(const short8*)(Bb + kk * 32);
        short8 b1 = *(const short8*)(Bb + 16 * A_STRIDE + kk * 32);
        short8 b2 = *(const short8*)(Bb + 32 * A_STRIDE + kk * 32);
        short8 b3 = *(const short8*)(Bb + 48 * A_STRIDE + kk * 32);
        MFMA8(acc, a0, a1, b0, b1, b2, b3)
    }
    #pragma unroll
    for (int ta = 0; ta < 2; ++ta) {
        #pragma unroll
        for (int r = 0; r < 4; ++r) {
            int el = et * 32 + ta * 16 + q * 4 + r;
            int d = dst[e0 + el];
            int* nrow = (int*)out + (size_t)d * 128;
            #pragma unroll
            for (int tb = 0; tb < 4; ++tb) {
                int o = nh * 64 + tb * 16 + li;
                float v = acc[ta][tb][r] + b_ne[o];
                v = v > 0.f ? v : 0.f;
                atomicMax(nrow + o, __float_as_int(v));
            }
        }
    }
}

__global__ __launch_bounds__(256) void node_direct(
    const float* __restrict__ nfeat, const float* __restrict__ b_self,
    const float* __restrict__ eps, const short* __restrict__ WselfB,
    float* __restrict__ out)
{
    __shared__ short As[64 * NS];
    __shared__ short Bs[128 * NS];
    const int tid = threadIdx.x;
    const int n0 = blockIdx.x * 64;
    {
        int r = tid >> 1, h = tid & 1;
        const short8* g = (const short8*)(WselfB + r * 128 + h * 64);
        short* l = Bs + r * NS + h * 64;
        #pragma unroll
        for (int c = 0; c < 8; ++c) *(short8*)(l + 8 * c) = g[c];
    }
    {
        int r = tid >> 2, fi = tid & 3;
        int n = n0 + r;
        if (n < NNODES) {
            const floatx4* row = (const floatx4*)(nfeat + (size_t)n * 128);
            #pragma unroll
            for (int p = 0; p < 8; ++p) {
                int f = fi + 4 * p;
                store_bf4(As + r * NS + 4 * f, row[f]);
            }
        } else {
            #pragma unroll
            for (int p = 0; p < 8; ++p) {
                int f = fi + 4 * p;
                *(short4v*)(As + r * NS + 4 * f) = (short4v){0, 0, 0, 0};
            }
        }
    }
    __syncthreads();
    const int lane = tid & 63;
    const int w = tid >> 6;
    const int et = w & 1, nh = w >> 1;
    const int li = lane & 15, q = lane >> 4;
    floatx4 acc[2][4];
    #pragma unroll
    for (int i = 0; i < 2; ++i)
        #pragma unroll
        for (int j = 0; j < 4; ++j)
            acc[i][j] = (floatx4){0.f, 0.f, 0.f, 0.f};
    const short* Ab = As + (et * 32 + li) * NS + q * 8;
    const short* Bb = Bs + (nh * 64 + li) * NS + q * 8;
    #pragma unroll
    for (int kk = 0; kk < 4; ++kk) {
        short8 a0 = *(const short8*)(Ab + kk * 32);
        short8 a1 = *(const short8*)(Ab + 16 * NS + kk * 32);
        short8 b0 = *(const short8*)(Bb + kk * 32);
        short8 b1 = *(const short8*)(Bb + 16 * NS + kk * 32);
        short8 b2 = *(const short8*)(Bb + 32 * NS + kk * 32);
        short8 b3 = *(const short8*)(Bb + 48 * NS + kk * 32);
        MFMA8(acc, a0, a1, b0, b1, b2, b3)
    }
    const float epsv = 1.0f + eps[0];
    #pragma unroll
    for (int ta = 0; ta < 2; ++ta) {
        #pragma unroll
        for (int r = 0; r < 4; ++r) {
            int n = n0 + et * 32 + ta * 16 + q * 4 + r;
            if (n < NNODES) {
                #pragma unroll
                for (int tb = 0; tb < 4; ++tb) {
                    int o = nh * 64 + tb * 16 + li;
                    float v = acc[ta][tb][r] + b_self[o]
                            + epsv * out[(size_t)n * 128 + o];
                    out[(size_t)n * 128 + o] = v;
                }
            }
        }
    }
}

// ---------------------------------------------------------------------------
extern "C" void kernel_launch(void* const* d_in, const int* in_sizes, int n_in,
                              void* d_out, int out_size, void* d_ws, size_t ws_size,
                              hipStream_t stream) {
    const float* nfeat  = (const float*)d_in[0];
    const float* etype  = (const float*)d_in[1];
    const int*   src    = (const int*)d_in[2];
    const int*   dst    = (const int*)d_in[3];
    const float* W_edge = (const float*)d_in[4];
    const float* W_ne   = (const float*)d_in[5];
    const float* b_ne   = (const float*)d_in[6];
    const float* W_self = (const float*)d_in[7];
    const float* b_self = (const float*)d_in[8];
    const float* eps    = (const float*)d_in[9];
    float* out = (float*)d_out;

    char* ws = (char*)d_ws;
    size_t off = 0;
    auto alloc = [&](size_t bytes) { void* p = ws + off; off = (off + bytes + 255) & ~(size_t)255; return p; };
    int*   cnt    = (int*)alloc((size_t)NNODES * 4);
    int*   cur    = (int*)alloc((size_t)NNODES * 4);
    int*   esd    = (int*)alloc((size_t)NEDGES * 4);
    short* escT   = (short*)alloc((size_t)NEDGES * EDGE_DIM * 2);
    short* nfB    = (short*)alloc((size_t)NNODES * IN_DIM * 2);
    short* WcatB  = (short*)alloc((size_t)OUT_DIM * KDIM * 2);
    short* WselfB = (short*)alloc((size_t)OUT_DIM * IN_DIM * 2);
    int*   bsum   = (int*)alloc((size_t)NSCB * 4);
    int*   boff   = (int*)alloc((size_t)NSCB * 4);
    size_t need = off;

    if (ws_size >= need) {
        hipMemsetAsync(cnt, 0, (size_t)NNODES * 4, stream);
        hipMemsetAsync(out, 0, (size_t)NNODES * OUT_DIM * sizeof(float), stream);
        prep_kernel<<<1024, 256, 0, stream>>>(nfeat, dst, W_edge, W_ne, W_self,
                                              cnt, nfB, WcatB, WselfB);
        scan_part<<<NSCB, 256, 0, stream>>>(cnt, bsum);
        scan_mid<<<1, 64, 0, stream>>>(bsum, boff);
        scan_write<<<NSCB, 256, 0, stream>>>(cnt, boff, cur);
        scatter_kernel<<<2048, 256, 0, stream>>>(src, dst, etype, cur, esd, escT);
        edge_kernel<<<EG, 256, 0, stream>>>(nfB, escT, esd, b_ne, WcatB, out);
        node_kernel<<<(NNODES + 63) / 64, 256, 0, stream>>>(nfB, b_self, eps,
                                                            WselfB, out);
    } else {
        short* WcatB2  = (short*)d_ws;
        short* WselfB2 = WcatB2 + (size_t)OUT_DIM * KDIM;
        hipMemsetAsync(out, 0, (size_t)NNODES * 128 * sizeof(float), stream);
        prep_w<<<144, 256, 0, stream>>>(W_edge, W_ne, W_self, WcatB2, WselfB2);
        edge_direct<<<NEDGES / 64, 256, 0, stream>>>(nfeat, etype, src, dst,
                                                     b_ne, WcatB2, out);
        node_direct<<<(NNODES + 63) / 64, 256, 0, stream>>>(nfeat, b_self, eps,
                                                            WselfB2, out);
    }
}